// Round 2
// baseline (5366.315 us; speedup 1.0000x reference)
//
#include <hip/hip_runtime.h>
#include <math.h>

#define TILE 64
#define KT 16
#define LDP (TILE + 4)

// ---------------- reduction helpers ----------------
__device__ __forceinline__ float wred_sum(float v) {
#pragma unroll
    for (int o = 32; o > 0; o >>= 1) v += __shfl_down(v, o, 64);
    return v;
}
__device__ __forceinline__ float wred_max(float v) {
#pragma unroll
    for (int o = 32; o > 0; o >>= 1) v = fmaxf(v, __shfl_down(v, o, 64));
    return v;
}

// ---------------- generic batched GEMM ----------------
// C = alpha * A @ op(B) + diag*I [+ bias] [+ residual C] [relu] [atomic splitK]
// bT=1: B is N x K row-major (C = A B^T). bT=0: B is K x N row-major.
// flags: 1 = add existing C (residual), 2 = relu, 4 = atomicAdd (splitK)
__global__ __launch_bounds__(256) void gemm_kernel(
    const float* __restrict__ A, const float* __restrict__ B, float* __restrict__ C,
    int M, int N, int K, int lda, int ldb, int ldc,
    long sA, long sB, long sC, int tilesN, int nSplit,
    float alpha, float diag, const float* __restrict__ bias, int flags, int bT) {
    int tm = blockIdx.x / tilesN, tn = blockIdx.x % tilesN;
    int batch = blockIdx.y / nSplit, split = blockIdx.y % nSplit;
    A += (long)batch * sA;
    B += (long)batch * sB;
    C += (long)batch * sC;
    int row0 = tm * TILE, col0 = tn * TILE;
    int k0s, k1;
    if (nSplit == 1) { k0s = 0; k1 = K; }
    else {
        int kc = ((((K + nSplit - 1) / nSplit) + KT - 1) / KT) * KT;
        k0s = split * kc;
        k1 = min(K, k0s + kc);
    }

    __shared__ float As[KT][LDP];
    __shared__ float Bs[KT][LDP];
    int t = threadIdx.x;
    int tx = t & 15, ty = t >> 4;
    float acc[4][4] = {{0.f}};
    int aRow = t >> 2;
    int aK = (t & 3) << 2;
    int bN = t & 63, bK = (t >> 6) << 2;

    for (int k0 = k0s; k0 < k1; k0 += KT) {
        {
            int r = row0 + aRow;
            float4 av = make_float4(0.f, 0.f, 0.f, 0.f);
            if (r < M) av = *(const float4*)(A + (long)r * lda + k0 + aK);
            As[aK][aRow] = av.x; As[aK + 1][aRow] = av.y;
            As[aK + 2][aRow] = av.z; As[aK + 3][aRow] = av.w;
        }
        if (bT) {
            int r = col0 + aRow;
            float4 bv = make_float4(0.f, 0.f, 0.f, 0.f);
            if (r < N) bv = *(const float4*)(B + (long)r * ldb + k0 + aK);
            Bs[aK][aRow] = bv.x; Bs[aK + 1][aRow] = bv.y;
            Bs[aK + 2][aRow] = bv.z; Bs[aK + 3][aRow] = bv.w;
        } else {
            const float* bp = B + (long)(k0 + bK) * ldb + col0 + bN;
#pragma unroll
            for (int j = 0; j < 4; j++) Bs[bK + j][bN] = bp[(long)j * ldb];
        }
        __syncthreads();
#pragma unroll
        for (int kk = 0; kk < KT; kk++) {
            float4 a = *(const float4*)&As[kk][ty << 2];
            float4 b = *(const float4*)&Bs[kk][tx << 2];
            acc[0][0] += a.x * b.x; acc[0][1] += a.x * b.y;
            acc[0][2] += a.x * b.z; acc[0][3] += a.x * b.w;
            acc[1][0] += a.y * b.x; acc[1][1] += a.y * b.y;
            acc[1][2] += a.y * b.z; acc[1][3] += a.y * b.w;
            acc[2][0] += a.z * b.x; acc[2][1] += a.z * b.y;
            acc[2][2] += a.z * b.z; acc[2][3] += a.z * b.w;
            acc[3][0] += a.w * b.x; acc[3][1] += a.w * b.y;
            acc[3][2] += a.w * b.z; acc[3][3] += a.w * b.w;
        }
        __syncthreads();
    }
#pragma unroll
    for (int i = 0; i < 4; i++) {
        int row = row0 + (ty << 2) + i;
        if (row >= M) continue;
        float* cp = C + (long)row * ldc + col0 + (tx << 2);
#pragma unroll
        for (int j = 0; j < 4; j++) {
            int col = col0 + (tx << 2) + j;
            if (col >= N) continue;
            float v = alpha * acc[i][j];
            if (row == col) v += diag;
            if (bias) v += bias[col];
            if (flags & 4) {
                atomicAdd(cp + j, v);
            } else {
                if (flags & 1) v += cp[j];
                if (flags & 2) v = fmaxf(v, 0.f);
                cp[j] = v;
            }
        }
    }
}

// ---------------- layernorm (rows of 512) ----------------
__global__ __launch_bounds__(256) void layernorm_rows(
    const float* __restrict__ x, const float* __restrict__ g,
    const float* __restrict__ b, float* __restrict__ y) {
    __shared__ float sm[4];
    long base = (long)blockIdx.x * 512;
    int t = threadIdx.x;
    float v0 = x[base + t], v1 = x[base + 256 + t];
    float s = wred_sum(v0 + v1);
    if ((t & 63) == 0) sm[t >> 6] = s;
    __syncthreads();
    float mu = (sm[0] + sm[1] + sm[2] + sm[3]) * (1.f / 512.f);
    __syncthreads();
    float d0 = v0 - mu, d1 = v1 - mu;
    float q = wred_sum(d0 * d0 + d1 * d1);
    if ((t & 63) == 0) sm[t >> 6] = q;
    __syncthreads();
    float var = (sm[0] + sm[1] + sm[2] + sm[3]) * (1.f / 512.f);
    float rstd = rsqrtf(var + 1e-5f);
    y[base + t] = d0 * rstd * g[t] + b[t];
    y[base + 256 + t] = d1 * rstd * g[256 + t] + b[256 + t];
}

// ---------------- softmax over rows ----------------
__global__ __launch_bounds__(256) void softmax_rows(float* __restrict__ data, int ncols) {
    __shared__ float sm[4];
    float* row = data + (long)blockIdx.x * ncols;
    int t = threadIdx.x;
    float m = -1e30f;
    for (int c = t; c < ncols; c += 256) m = fmaxf(m, row[c]);
    m = wred_max(m);
    if ((t & 63) == 0) sm[t >> 6] = m;
    __syncthreads();
    m = fmaxf(fmaxf(sm[0], sm[1]), fmaxf(sm[2], sm[3]));
    __syncthreads();
    float s = 0.f;
    for (int c = t; c < ncols; c += 256) {
        float e = expf(row[c] - m);
        row[c] = e;
        s += e;
    }
    s = wred_sum(s);
    if ((t & 63) == 0) sm[t >> 6] = s;
    __syncthreads();
    s = sm[0] + sm[1] + sm[2] + sm[3];
    float inv = 1.f / s;
    for (int c = t; c < ncols; c += 256) row[c] *= inv;
}

// ---------------- misc small kernels ----------------
__global__ void scale_q(float* __restrict__ qkv) {
    long idx = (long)blockIdx.x * 256 + threadIdx.x;
    long row = idx >> 9;
    int c = (int)(idx & 511);
    qkv[row * 1536 + c] *= 0.125f;  // DIM_HEAD^-0.5
}

__global__ void cls_copy(const float* __restrict__ cls, float* __restrict__ X) {
    X[threadIdx.x] = cls[threadIdx.x];
}

__global__ void landmarks_kernel(const float* __restrict__ qkv,
                                 float* __restrict__ ql, float* __restrict__ kl) {
    int h = blockIdx.x >> 8, j = blockIdx.x & 255, d = threadIdx.x;
    const float* base = qkv + (long)j * 64 * 1536 + h * 64 + d;
    float sq = 0.f, sk = 0.f;
    for (int tk = 0; tk < 64; ++tk) {
        sq += base[(long)tk * 1536];
        sk += base[(long)tk * 1536 + 512];
    }
    ql[((h << 8) + j) * 64 + d] = sq * (1.f / 64.f);
    kl[((h << 8) + j) * 64 + d] = sk * (1.f / 64.f);
}

__global__ __launch_bounds__(256) void pinv_absmax(const float* __restrict__ a2,
                                                   float* __restrict__ maxes) {
    __shared__ float sm[4];
    const float* Xh = a2 + (long)blockIdx.x * 65536;
    int t = threadIdx.x;
    float cs = 0.f, rs = 0.f;
    for (int j = 0; j < 256; j++) {
        cs += fabsf(Xh[t * 256 + j]);
        rs += fabsf(Xh[j * 256 + t]);
    }
    float cm = wred_max(cs);
    if ((t & 63) == 0) sm[t >> 6] = cm;
    __syncthreads();
    cm = fmaxf(fmaxf(sm[0], sm[1]), fmaxf(sm[2], sm[3]));
    if (t == 0) atomicMax((int*)&maxes[0], __float_as_int(cm));
    __syncthreads();
    float rm = wred_max(rs);
    if ((t & 63) == 0) sm[t >> 6] = rm;
    __syncthreads();
    rm = fmaxf(fmaxf(sm[0], sm[1]), fmaxf(sm[2], sm[3]));
    if (t == 0) atomicMax((int*)&maxes[1], __float_as_int(rm));
}

__global__ void pinv_init(const float* __restrict__ a2, const float* __restrict__ maxes,
                          float* __restrict__ z) {
    long idx = (long)blockIdx.x * 256 + threadIdx.x;
    int h = (int)(idx >> 16);
    int rem = (int)(idx & 65535);
    int i = rem >> 8, j = rem & 255;
    float inv = 1.f / (maxes[0] * maxes[1]);
    z[idx] = a2[((long)h << 16) + (j << 8) + i] * inv;
}

__global__ void neg_diag(const float* __restrict__ in, float* __restrict__ out, float dv) {
    long idx = (long)blockIdx.x * 256 + threadIdx.x;
    int i = (int)((idx >> 8) & 255), j = (int)(idx & 255);
    out[idx] = ((i == j) ? dv : 0.f) - in[idx];
}

__global__ void conv_residual(const float* __restrict__ qkv, const float* __restrict__ cw,
                              float* __restrict__ attn) {
    long idx = (long)blockIdx.x * 256 + threadIdx.x;
    int i = (int)(idx >> 9);
    int c = (int)(idx & 511);
    const float* w = cw + (c >> 6) * 33;
    float s = 0.f;
#pragma unroll
    for (int k = 0; k < 33; k++) {
        int ii = i + k - 16;
        if (ii >= 0 && ii < 16384) s += w[k] * qkv[(long)ii * 1536 + 1024 + c];
    }
    attn[idx] += s;
}

__global__ __launch_bounds__(256) void final_head(
    const float* __restrict__ X, const float* __restrict__ g, const float* __restrict__ b,
    const float* __restrict__ W, const float* __restrict__ bias, float* __restrict__ out) {
    __shared__ float sm[4];
    __shared__ float ln0[512];
    int t = threadIdx.x;
    float v0 = X[t], v1 = X[256 + t];
    float s = wred_sum(v0 + v1);
    if ((t & 63) == 0) sm[t >> 6] = s;
    __syncthreads();
    float mu = (sm[0] + sm[1] + sm[2] + sm[3]) * (1.f / 512.f);
    __syncthreads();
    float d0 = v0 - mu, d1 = v1 - mu;
    float q = wred_sum(d0 * d0 + d1 * d1);
    if ((t & 63) == 0) sm[t >> 6] = q;
    __syncthreads();
    float rstd = rsqrtf((sm[0] + sm[1] + sm[2] + sm[3]) * (1.f / 512.f) + 1e-5f);
    ln0[t] = d0 * rstd * g[t] + b[t];
    ln0[256 + t] = d1 * rstd * g[256 + t] + b[256 + t];
    __syncthreads();
    int jj = blockIdx.x * 256 + t;
    if (jj < 1000) {
        float acc = bias[jj];
        for (int dd = 0; dd < 512; ++dd) acc += ln0[dd] * W[dd * 1000 + jj];
        out[jj] = acc;
    }
}

// ---------------- host helpers ----------------
static void gemm(hipStream_t st, int bT, int M, int N, int K,
                 const float* A, int lda, long sA,
                 const float* B, int ldb, long sB,
                 float* C, int ldc, long sC,
                 int batch, int nSplit, float alpha, float diag,
                 const float* bias, int flags) {
    int tilesM = (M + TILE - 1) / TILE, tilesN = (N + TILE - 1) / TILE;
    dim3 grid(tilesM * tilesN, batch * nSplit);
    hipLaunchKernelGGL(gemm_kernel, grid, dim3(256), 0, st,
                       A, B, C, M, N, K, lda, ldb, ldc, sA, sB, sC,
                       tilesN, nSplit, alpha, diag, bias, flags, bT);
}

static void run_layer(hipStream_t st, int g, float* X, float* LNA, float* QKV,
                      float* BIG, float* A2, float* Z0, float* Z1,
                      float* XZ, float* T1, float* T2,
                      float* QL, float* KL, float* A3V, float* W2, float* MAXES,
                      const float* ln_g, const float* ln_b, const float* qkv_W,
                      const float* conv_W, const float* out_W, const float* out_b) {
    const int N = 16384, D = 512, H = 8, DH = 64, M = 256;
    // 1. LN = layernorm(X)   (LNA buffer; dead after qkv gemm, then reused as ATTN)
    layernorm_rows<<<N, 256, 0, st>>>(X, ln_g, ln_b, LNA);
    // 2. qkv = LN @ qkv_W  [16384 x 1536]; scale q
    gemm(st, 0, N, 3 * D, D, LNA, D, 0, qkv_W, 3 * D, 0, QKV, 3 * D, 0, 1, 1, 1.f, 0.f, nullptr, 0);
    scale_q<<<(N * D) / 256, 256, 0, st>>>(QKV);
    // 3. landmarks
    landmarks_kernel<<<H * M, 64, 0, st>>>(QKV, QL, KL);
    // 4. sim2 -> softmax -> pinv (batched over all 8 heads; small)
    gemm(st, 1, M, M, DH, QL, DH, (long)M * DH, KL, DH, (long)M * DH,
         A2, M, (long)M * M, H, 1, 1.f, 0.f, nullptr, 0);
    softmax_rows<<<H * M, 256, 0, st>>>(A2, M);
    hipMemsetAsync(MAXES, 0, 8, st);
    pinv_absmax<<<H, 256, 0, st>>>(A2, MAXES);
    pinv_init<<<(H * M * M) / 256, 256, 0, st>>>(A2, MAXES, Z0);
    float* z = Z0;
    float* zn = Z1;
    for (int it = 0; it < 6; ++it) {
        gemm(st, 0, M, M, M, A2, M, (long)M * M, z, M, (long)M * M,
             XZ, M, (long)M * M, H, 1, 1.f, 0.f, nullptr, 0);
        neg_diag<<<(H * M * M) / 256, 256, 0, st>>>(XZ, T1, 7.f);
        gemm(st, 0, M, M, M, XZ, M, (long)M * M, T1, M, (long)M * M,
             T2, M, (long)M * M, H, 1, -1.f, 15.f, nullptr, 0);
        gemm(st, 0, M, M, M, XZ, M, (long)M * M, T2, M, (long)M * M,
             T1, M, (long)M * M, H, 1, -1.f, 13.f, nullptr, 0);
        gemm(st, 0, M, M, M, z, M, (long)M * M, T1, M, (long)M * M,
             zn, M, (long)M * M, H, 1, 0.25f, 0.f, nullptr, 0);
        float* tmp = z; z = zn; zn = tmp;
    }
    // 5. per head-group: sim3 = q_l @ k^T -> softmax -> a3v  (BIG reused per group)
    int nSplit = (g == 8) ? 8 : 32;
    for (int hg = 0; hg < H; hg += g) {
        gemm(st, 1, M, N, DH, QL + (long)hg * M * DH, DH, (long)M * DH,
             QKV + D + hg * DH, 3 * D, (long)DH,
             BIG, N, (long)M * N, g, 1, 1.f, 0.f, nullptr, 0);
        softmax_rows<<<g * M, 256, 0, st>>>(BIG, N);
        hipMemsetAsync(A3V + (long)hg * M * DH, 0, (size_t)g * M * DH * 4, st);
        gemm(st, 0, M, DH, N, BIG, N, (long)M * N,
             QKV + 2 * D + hg * DH, 3 * D, (long)DH,
             A3V + (long)hg * M * DH, DH, (long)M * DH, g, nSplit, 1.f, 0.f, nullptr, 4);
    }
    // 6. W2 = a2inv @ a3v  [8 x 256 x 64]  (re-association: out = a1 @ W2)
    gemm(st, 0, M, DH, M, z, M, (long)M * M, A3V, DH, (long)M * DH,
         W2, DH, (long)M * DH, H, 1, 1.f, 0.f, nullptr, 0);
    // 7. per head-group: sim1 = q @ k_l^T -> softmax -> ATTN cols = a1 @ W2
    for (int hg = 0; hg < H; hg += g) {
        gemm(st, 1, N, M, DH, QKV + hg * DH, 3 * D, (long)DH,
             KL + (long)hg * M * DH, DH, (long)M * DH,
             BIG, M, (long)N * M, g, 1, 1.f, 0.f, nullptr, 0);
        softmax_rows<<<g * N, 256, 0, st>>>(BIG, M);
        gemm(st, 0, N, DH, M, BIG, M, (long)N * M,
             W2 + (long)hg * M * DH, DH, (long)M * DH,
             LNA + hg * DH, D, (long)DH, g, 1, 1.f, 0.f, nullptr, 0);
    }
    // 8. conv residual into ATTN (=LNA)
    conv_residual<<<(N * D) / 256, 256, 0, st>>>(QKV, conv_W, LNA);
    // 9. X = X + ATTN @ out_W + out_b
    gemm(st, 0, N, D, D, LNA, D, 0, out_W, D, 0, X, D, 0, 1, 1, 1.f, 0.f, out_b, 1);
}

extern "C" void kernel_launch(void* const* d_in, const int* in_sizes, int n_in,
                              void* d_out, int out_size, void* d_ws, size_t ws_size,
                              hipStream_t stream) {
    const float* h_in = (const float*)d_in[0];
    const float* W1 = (const float*)d_in[1];
    const float* b1 = (const float*)d_in[2];
    const float* cls = (const float*)d_in[3];
    const float* ln1_g = (const float*)d_in[4];
    const float* ln1_b = (const float*)d_in[5];
    const float* qkv1_W = (const float*)d_in[6];
    const float* conv1_W = (const float*)d_in[7];
    const float* out1_W = (const float*)d_in[8];
    const float* out1_b = (const float*)d_in[9];
    const float* ln2_g = (const float*)d_in[10];
    const float* ln2_b = (const float*)d_in[11];
    const float* qkv2_W = (const float*)d_in[12];
    const float* conv2_W = (const float*)d_in[13];
    const float* out2_W = (const float*)d_in[14];
    const float* out2_b = (const float*)d_in[15];
    const float* lnf_g = (const float*)d_in[16];
    const float* lnf_b = (const float*)d_in[17];
    const float* fc2_W = (const float*)d_in[18];
    const float* fc2_b = (const float*)d_in[19];
    float* out = (float*)d_out;

    char* wsb = (char*)d_ws;
    size_t off = 0;
    auto alloc = [&](size_t bytes) -> float* {
        float* p = (float*)(wsb + off);
        off += (bytes + 255) & ~(size_t)255;
        return p;
    };
    // fixed buffers (~183 MB)
    float* X   = alloc((size_t)16384 * 512 * 4);   // residual stream
    float* LNA = alloc((size_t)16384 * 512 * 4);   // LN output, then ATTN
    float* QKV = alloc((size_t)16384 * 1536 * 4);
    float* A2  = alloc((size_t)8 * 256 * 256 * 4);
    float* Z0  = alloc((size_t)8 * 256 * 256 * 4);
    float* Z1  = alloc((size_t)8 * 256 * 256 * 4);
    float* XZ  = alloc((size_t)8 * 256 * 256 * 4);
    float* T1  = alloc((size_t)8 * 256 * 256 * 4);
    float* T2  = alloc((size_t)8 * 256 * 256 * 4);
    float* QL  = alloc((size_t)8 * 256 * 64 * 4);
    float* KL  = alloc((size_t)8 * 256 * 64 * 4);
    float* A3V = alloc((size_t)8 * 256 * 64 * 4);
    float* W2  = alloc((size_t)8 * 256 * 64 * 4);
    float* MAXES = alloc(256);
    // BIG: [g x 256 x 16384]; g=8 needs ~317 MB total, g=1 needs ~200 MB.
    size_t fixed = off;
    size_t bigOne = (size_t)256 * 16384 * 4;
    int g = (ws_size >= fixed + 8 * bigOne + 4096) ? 8 : 1;
    float* BIG = alloc((size_t)g * bigOne);
    if (off > ws_size) return;  // workspace too small -> output stays zero (fails loudly)

    // fc1: X[1:] = relu(h @ W1 + b1); X[0] = cls
    gemm(stream, 0, 16383, 512, 1024, h_in, 1024, 0, W1, 512, 0,
         X + 512, 512, 0, 1, 1, 1.f, 0.f, b1, 2);
    cls_copy<<<1, 512, 0, stream>>>(cls, X);

    run_layer(stream, g, X, LNA, QKV, BIG, A2, Z0, Z1, XZ, T1, T2,
              QL, KL, A3V, W2, MAXES, ln1_g, ln1_b, qkv1_W, conv1_W, out1_W, out1_b);
    run_layer(stream, g, X, LNA, QKV, BIG, A2, Z0, Z1, XZ, T1, T2,
              QL, KL, A3V, W2, MAXES, ln2_g, ln2_b, qkv2_W, conv2_W, out2_W, out2_b);

    final_head<<<4, 256, 0, stream>>>(X, lnf_g, lnf_b, fc2_W, fc2_b, out);
}

// Round 3
// 2692.437 us; speedup vs baseline: 1.9931x; 1.9931x over previous
//
#include <hip/hip_runtime.h>
#include <math.h>

typedef unsigned short u16;
typedef short bf16x8 __attribute__((ext_vector_type(8)));
typedef float f32x4 __attribute__((ext_vector_type(4)));

__device__ __forceinline__ u16 f2b(float x) {
    unsigned u = __builtin_bit_cast(unsigned, x);
    unsigned r = u + 0x7fffu + ((u >> 16) & 1u);
    return (u16)(r >> 16);
}
__device__ __forceinline__ float b2f(u16 v) {
    return __builtin_bit_cast(float, (unsigned)v << 16);
}
__device__ __forceinline__ void gl_lds16(const u16* g, u16* l) {
    __builtin_amdgcn_global_load_lds(
        (const __attribute__((address_space(1))) unsigned int*)g,
        (__attribute__((address_space(3))) unsigned int*)l, 16, 0, 0);
}
__device__ __forceinline__ float wred_sum(float v) {
#pragma unroll
    for (int o = 32; o > 0; o >>= 1) v += __shfl_down(v, o, 64);
    return v;
}
__device__ __forceinline__ float wred_max(float v) {
#pragma unroll
    for (int o = 32; o > 0; o >>= 1) v = fmaxf(v, __shfl_down(v, o, 64));
    return v;
}

// ================= bf16 MFMA GEMM (NT): C[M][N] = A[M][K] @ B[N][K]^T ==========
// MODE: 0 plain fp32 C; 1 bias+relu; 2 C += acc + bias (residual); 3 atomicAdd;
//       4 qkv-split bf16 (q*0.125->Q [h][n][64], k->Kb, v->V^T [h*64+d][n]);
//       5 C[row][colOfs + batch*64 + col] += acc   (a1@W2 into ATTN columns)
struct GP {
    const u16* A; const u16* B; float* C;
    u16* Q; u16* Kb; u16* V;
    const float* bias;
    long sA, sB, sC;
    int K, ldc, tilesN, nSplit, colOfs;
};

template <int BM, int BN, int MODE>
__global__ __launch_bounds__(256) void mgemm(GP p) {
    constexpr int WN = BN / 64;          // waves in N
    constexpr int LA = BM / 64;          // global_load_lds calls per wave for A
    constexpr int LB = BN / 64;
    __shared__ u16 As[BM * 32] __attribute__((aligned(16)));
    __shared__ u16 Bs[BN * 32] __attribute__((aligned(16)));

    int tid = threadIdx.x, lane = tid & 63, wave = tid >> 6;
    int wm = wave / WN, wn = wave % WN;
    int tm = blockIdx.x / p.tilesN, tn = blockIdx.x % p.tilesN;
    int batch = blockIdx.y / p.nSplit, split = blockIdx.y % p.nSplit;
    int m0 = tm * BM, n0 = tn * BN;
    const u16* A = p.A + (long)batch * p.sA;
    const u16* B = p.B + (long)batch * p.sB;

    int kc = (((p.K + p.nSplit - 1) / p.nSplit + 31) / 32) * 32;
    int k0s = split * kc;
    int k1 = min(p.K, k0s + kc);

    f32x4 acc[4][4];
#pragma unroll
    for (int i = 0; i < 4; i++)
#pragma unroll
        for (int j = 0; j < 4; j++) acc[i][j] = (f32x4){0.f, 0.f, 0.f, 0.f};

    int lr = lane >> 2;              // 0..15 row-within-chunk
    int lcb = (lane & 3) * 8;        // k element offset
    for (int k0 = k0s; k0 < k1; k0 += 32) {
#pragma unroll
        for (int i = 0; i < LA; i++) {
            int chunk = wave * LA + i;
            gl_lds16(A + (long)(m0 + chunk * 16 + lr) * p.K + k0 + lcb,
                     As + chunk * 512 + lane * 8);
        }
#pragma unroll
        for (int i = 0; i < LB; i++) {
            int chunk = wave * LB + i;
            gl_lds16(B + (long)(n0 + chunk * 16 + lr) * p.K + k0 + lcb,
                     Bs + chunk * 512 + lane * 8);
        }
        __syncthreads();
        bf16x8 af[4], bfv[4];
        int mrow = (lane & 15), kq = (lane >> 4) * 8;
#pragma unroll
        for (int mi = 0; mi < 4; mi++)
            af[mi] = *(const bf16x8*)(As + (wm * 64 + mi * 16 + mrow) * 32 + kq);
#pragma unroll
        for (int ni = 0; ni < 4; ni++)
            bfv[ni] = *(const bf16x8*)(Bs + (wn * 64 + ni * 16 + mrow) * 32 + kq);
#pragma unroll
        for (int mi = 0; mi < 4; mi++)
#pragma unroll
            for (int ni = 0; ni < 4; ni++)
                acc[mi][ni] = __builtin_amdgcn_mfma_f32_16x16x32_bf16(
                    af[mi], bfv[ni], acc[mi][ni], 0, 0, 0);
        __syncthreads();
    }

    float* C = p.C + (long)batch * p.sC;
    int quad = lane >> 4, cn = lane & 15;
#pragma unroll
    for (int mi = 0; mi < 4; mi++) {
#pragma unroll
        for (int ni = 0; ni < 4; ni++) {
#pragma unroll
            for (int r = 0; r < 4; r++) {
                int row = m0 + wm * 64 + mi * 16 + quad * 4 + r;
                int col = n0 + wn * 64 + ni * 16 + cn;
                float v = acc[mi][ni][r];
                if (MODE == 0) {
                    C[(long)row * p.ldc + col] = v;
                } else if (MODE == 1) {
                    C[(long)row * p.ldc + col] = fmaxf(v + p.bias[col], 0.f);
                } else if (MODE == 2) {
                    C[(long)row * p.ldc + col] += v + p.bias[col];
                } else if (MODE == 3) {
                    atomicAdd(&C[(long)row * p.ldc + col], v);
                } else if (MODE == 4) {
                    if (col < 512) {
                        int h = col >> 6, d = col & 63;
                        p.Q[((long)h * 16384 + row) * 64 + d] = f2b(v * 0.125f);
                    } else if (col < 1024) {
                        int h = (col - 512) >> 6, d = col & 63;
                        p.Kb[((long)h * 16384 + row) * 64 + d] = f2b(v);
                    } else {
                        p.V[(long)(col - 1024) * 16384 + row] = f2b(v);
                    }
                } else if (MODE == 5) {
                    C[(long)row * p.ldc + p.colOfs + batch * 64 + col] += v;
                }
            }
        }
    }
}

template <int BM, int BN, int MODE>
static void launch_mgemm(hipStream_t st, const u16* A, const u16* B, float* C,
                         u16* Q, u16* Kb, u16* V, const float* bias,
                         long sA, long sB, long sC, int M, int N, int K,
                         int ldc, int batch, int nSplit, int colOfs) {
    GP p{A, B, C, Q, Kb, V, bias, sA, sB, sC, K, ldc, N / BN, nSplit, colOfs};
    dim3 grid((M / BM) * (N / BN), batch * nSplit);
    mgemm<BM, BN, MODE><<<grid, 256, 0, st>>>(p);
}

// ================= fp32 tile GEMM (pinv path only) =============================
#define TILE 64
#define KT 16
#define LDP (TILE + 4)
__global__ __launch_bounds__(256) void gemm_kernel(
    const float* __restrict__ A, const float* __restrict__ B, float* __restrict__ C,
    int M, int N, int K, int lda, int ldb, int ldc,
    long sA, long sB, long sC, int tilesN,
    float alpha, float diag, int flags) {
    int tm = blockIdx.x / tilesN, tn = blockIdx.x % tilesN;
    int batch = blockIdx.y;
    A += (long)batch * sA; B += (long)batch * sB; C += (long)batch * sC;
    int row0 = tm * TILE, col0 = tn * TILE;
    __shared__ float As[KT][LDP];
    __shared__ float Bs[KT][LDP];
    int t = threadIdx.x;
    int tx = t & 15, ty = t >> 4;
    float acc[4][4] = {{0.f}};
    int aRow = t >> 2, aK = (t & 3) << 2;
    int bN = t & 63, bK = (t >> 6) << 2;
    for (int k0 = 0; k0 < K; k0 += KT) {
        {
            int r = row0 + aRow;
            float4 av = make_float4(0.f, 0.f, 0.f, 0.f);
            if (r < M) av = *(const float4*)(A + (long)r * lda + k0 + aK);
            As[aK][aRow] = av.x; As[aK + 1][aRow] = av.y;
            As[aK + 2][aRow] = av.z; As[aK + 3][aRow] = av.w;
        }
        {
            const float* bp = B + (long)(k0 + bK) * ldb + col0 + bN;
            bool ok = col0 + bN < N;
#pragma unroll
            for (int j = 0; j < 4; j++) Bs[bK + j][bN] = ok ? bp[(long)j * ldb] : 0.f;
        }
        __syncthreads();
#pragma unroll
        for (int kk = 0; kk < KT; kk++) {
            float4 a = *(const float4*)&As[kk][ty << 2];
            float4 b = *(const float4*)&Bs[kk][tx << 2];
            acc[0][0] += a.x * b.x; acc[0][1] += a.x * b.y; acc[0][2] += a.x * b.z; acc[0][3] += a.x * b.w;
            acc[1][0] += a.y * b.x; acc[1][1] += a.y * b.y; acc[1][2] += a.y * b.z; acc[1][3] += a.y * b.w;
            acc[2][0] += a.z * b.x; acc[2][1] += a.z * b.y; acc[2][2] += a.z * b.z; acc[2][3] += a.z * b.w;
            acc[3][0] += a.w * b.x; acc[3][1] += a.w * b.y; acc[3][2] += a.w * b.z; acc[3][3] += a.w * b.w;
        }
        __syncthreads();
    }
#pragma unroll
    for (int i = 0; i < 4; i++) {
        int row = row0 + (ty << 2) + i;
        if (row >= M) continue;
        float* cp = C + (long)row * ldc + col0 + (tx << 2);
#pragma unroll
        for (int j = 0; j < 4; j++) {
            int col = col0 + (tx << 2) + j;
            if (col >= N) continue;
            float v = alpha * acc[i][j];
            if (row == col) v += diag;
            if (flags & 1) v += cp[j];
            cp[j] = v;
        }
    }
}
static void gemm32(hipStream_t st, int M, int N, int K,
                   const float* A, int lda, long sA,
                   const float* B, int ldb, long sB,
                   float* C, int ldc, long sC,
                   int batch, float alpha, float diag, int flags) {
    int tilesM = (M + TILE - 1) / TILE, tilesN = (N + TILE - 1) / TILE;
    dim3 grid(tilesM * tilesN, batch);
    gemm_kernel<<<grid, 256, 0, st>>>(A, B, C, M, N, K, lda, ldb, ldc, sA, sB, sC,
                                      tilesN, alpha, diag, flags);
}

// ================= layernorm rows of 512 -> bf16 ==============================
__global__ __launch_bounds__(256) void layernorm_bf16(
    const float* __restrict__ x, const float* __restrict__ g,
    const float* __restrict__ b, u16* __restrict__ y) {
    __shared__ float sm[4];
    long base = (long)blockIdx.x * 512;
    int t = threadIdx.x;
    float v0 = x[base + t], v1 = x[base + 256 + t];
    float s = wred_sum(v0 + v1);
    if ((t & 63) == 0) sm[t >> 6] = s;
    __syncthreads();
    float mu = (sm[0] + sm[1] + sm[2] + sm[3]) * (1.f / 512.f);
    __syncthreads();
    float d0 = v0 - mu, d1 = v1 - mu;
    float q = wred_sum(d0 * d0 + d1 * d1);
    if ((t & 63) == 0) sm[t >> 6] = q;
    __syncthreads();
    float var = (sm[0] + sm[1] + sm[2] + sm[3]) * (1.f / 512.f);
    float rstd = rsqrtf(var + 1e-5f);
    y[base + t] = f2b(d0 * rstd * g[t] + b[t]);
    y[base + 256 + t] = f2b(d1 * rstd * g[256 + t] + b[256 + t]);
}

// ================= softmax fp32 in-place (A2) ==================================
__global__ __launch_bounds__(256) void softmax_rows(float* __restrict__ data, int ncols) {
    __shared__ float sm[4];
    float* row = data + (long)blockIdx.x * ncols;
    int t = threadIdx.x;
    float m = -1e30f;
    for (int c = t; c < ncols; c += 256) m = fmaxf(m, row[c]);
    m = wred_max(m);
    if ((t & 63) == 0) sm[t >> 6] = m;
    __syncthreads();
    m = fmaxf(fmaxf(sm[0], sm[1]), fmaxf(sm[2], sm[3]));
    __syncthreads();
    float s = 0.f;
    for (int c = t; c < ncols; c += 256) {
        float e = expf(row[c] - m);
        row[c] = e;
        s += e;
    }
    s = wred_sum(s);
    if ((t & 63) == 0) sm[t >> 6] = s;
    __syncthreads();
    s = sm[0] + sm[1] + sm[2] + sm[3];
    float inv = 1.f / s;
    for (int c = t; c < ncols; c += 256) row[c] *= inv;
}

// ================= softmax fp32 src -> bf16 dst ================================
__global__ __launch_bounds__(256) void softmax_bf16(
    const float* __restrict__ src, u16* __restrict__ dst, int ncols) {
    __shared__ float sm[4];
    const float* row = src + (long)blockIdx.x * ncols;
    u16* drow = dst + (long)blockIdx.x * ncols;
    int t = threadIdx.x;
    float m = -1e30f;
    for (int c = t; c < ncols; c += 256) m = fmaxf(m, row[c]);
    m = wred_max(m);
    if ((t & 63) == 0) sm[t >> 6] = m;
    __syncthreads();
    m = fmaxf(fmaxf(sm[0], sm[1]), fmaxf(sm[2], sm[3]));
    __syncthreads();
    float s = 0.f;
    for (int c = t; c < ncols; c += 256) s += expf(row[c] - m);
    s = wred_sum(s);
    if ((t & 63) == 0) sm[t >> 6] = s;
    __syncthreads();
    s = sm[0] + sm[1] + sm[2] + sm[3];
    float inv = 1.f / s;
    for (int c = t; c < ncols; c += 256) drow[c] = f2b(expf(row[c] - m) * inv);
}

// ================= small utility kernels ======================================
__global__ void cls_copy(const float* __restrict__ cls, float* __restrict__ X) {
    X[threadIdx.x] = cls[threadIdx.x];
}
__global__ void build_hb(const float* __restrict__ h, u16* __restrict__ dst) {
    long idx = (long)blockIdx.x * 256 + threadIdx.x;  // 16384*1024
    long row = idx >> 10;
    int col = (int)(idx & 1023);
    float v = (row == 0) ? 0.f : h[((row - 1) << 10) + col];
    dst[idx] = f2b(v);
}
__global__ void transpose_to_bf16(const float* __restrict__ src, u16* __restrict__ dst,
                                  int R, int C) {
    long idx = (long)blockIdx.x * 256 + threadIdx.x;
    if (idx >= (long)R * C) return;
    int r = (int)(idx / C), c = (int)(idx % C);
    dst[(long)c * R + r] = f2b(src[idx]);
}
__global__ void cvt_bf16_vec(const float* __restrict__ src, u16* __restrict__ dst, long n4) {
    long i = (long)blockIdx.x * 256 + threadIdx.x;
    if (i >= n4) return;
    float4 v = ((const float4*)src)[i];
    union { u16 h[4]; uint2 u; } o;
    o.h[0] = f2b(v.x); o.h[1] = f2b(v.y); o.h[2] = f2b(v.z); o.h[3] = f2b(v.w);
    ((uint2*)dst)[i] = o.u;
}
// landmark means from bf16 Q/K [h][n][64] -> bf16 [h][256][64]
__global__ void landmarks_b(const u16* __restrict__ Qb, const u16* __restrict__ Kb,
                            u16* __restrict__ QLb, u16* __restrict__ KLb) {
    int h = blockIdx.x >> 8, j = blockIdx.x & 255, d = threadIdx.x;
    const u16* qb = Qb + ((long)h * 16384 + j * 64) * 64 + d;
    const u16* kb = Kb + ((long)h * 16384 + j * 64) * 64 + d;
    float sq = 0.f, sk = 0.f;
    for (int tk = 0; tk < 64; ++tk) {
        sq += b2f(qb[tk * 64]);
        sk += b2f(kb[tk * 64]);
    }
    QLb[((h << 8) + j) * 64 + d] = f2b(sq * (1.f / 64.f));
    KLb[((h << 8) + j) * 64 + d] = f2b(sk * (1.f / 64.f));
}
__global__ __launch_bounds__(256) void pinv_absmax(const float* __restrict__ a2,
                                                   float* __restrict__ maxes) {
    __shared__ float sm[4];
    const float* Xh = a2 + (long)blockIdx.x * 65536;
    int t = threadIdx.x;
    float cs = 0.f, rs = 0.f;
    for (int j = 0; j < 256; j++) {
        cs += fabsf(Xh[t * 256 + j]);
        rs += fabsf(Xh[j * 256 + t]);
    }
    float cm = wred_max(cs);
    if ((t & 63) == 0) sm[t >> 6] = cm;
    __syncthreads();
    cm = fmaxf(fmaxf(sm[0], sm[1]), fmaxf(sm[2], sm[3]));
    if (t == 0) atomicMax((int*)&maxes[0], __float_as_int(cm));
    __syncthreads();
    float rm = wred_max(rs);
    if ((t & 63) == 0) sm[t >> 6] = rm;
    __syncthreads();
    rm = fmaxf(fmaxf(sm[0], sm[1]), fmaxf(sm[2], sm[3]));
    if (t == 0) atomicMax((int*)&maxes[1], __float_as_int(rm));
}
__global__ void pinv_init(const float* __restrict__ a2, const float* __restrict__ maxes,
                          float* __restrict__ z) {
    long idx = (long)blockIdx.x * 256 + threadIdx.x;
    int h = (int)(idx >> 16);
    int rem = (int)(idx & 65535);
    int i = rem >> 8, j = rem & 255;
    float inv = 1.f / (maxes[0] * maxes[1]);
    z[idx] = a2[((long)h << 16) + (j << 8) + i] * inv;
}
__global__ void neg_diag(const float* __restrict__ in, float* __restrict__ out, float dv) {
    long idx = (long)blockIdx.x * 256 + threadIdx.x;
    int i = (int)((idx >> 8) & 255), j = (int)(idx & 255);
    out[idx] = ((i == j) ? dv : 0.f) - in[idx];
}
// depthwise conv over n from V^T bf16 [h*64+d][n]; writes ATTN[n][h*64+d] (init, not +=)
__global__ __launch_bounds__(256) void conv_kernel(const u16* __restrict__ VT,
                                                   const float* __restrict__ cw,
                                                   float* __restrict__ out) {
    int h = blockIdx.y;
    int n0 = blockIdx.x * 64;
    __shared__ float vt[64][97];
    int t = threadIdx.x;
    for (int i = t; i < 64 * 96; i += 256) {
        int d = i / 96, j = i % 96;
        int n = n0 - 16 + j;
        float v = 0.f;
        if (n >= 0 && n < 16384) v = b2f(VT[((long)h * 64 + d) * 16384 + n]);
        vt[d][j] = v;
    }
    __syncthreads();
    float w[33];
#pragma unroll
    for (int k = 0; k < 33; k++) w[k] = cw[h * 33 + k];
    int d = t & 63, ty = t >> 6;
    for (int nn = 0; nn < 16; nn++) {
        int nl = ty * 16 + nn;
        float s = 0.f;
#pragma unroll
        for (int k = 0; k < 33; k++) s += w[k] * vt[d][nl + k];
        out[((long)(n0 + nl)) * 512 + h * 64 + d] = s;
    }
}
__global__ void w2t_kernel(const float* __restrict__ W2, u16* __restrict__ W2T) {
    int idx = blockIdx.x * 256 + threadIdx.x;  // 8*256*64
    int h = idx >> 14, rem = idx & 16383, m = rem >> 6, d = rem & 63;
    W2T[(h << 14) + (d << 8) + m] = f2b(W2[idx]);
}
__global__ __launch_bounds__(256) void final_head(
    const float* __restrict__ X, const float* __restrict__ g, const float* __restrict__ b,
    const float* __restrict__ W, const float* __restrict__ bias, float* __restrict__ out) {
    __shared__ float sm[4];
    __shared__ float ln0[512];
    int t = threadIdx.x;
    float v0 = X[t], v1 = X[256 + t];
    float s = wred_sum(v0 + v1);
    if ((t & 63) == 0) sm[t >> 6] = s;
    __syncthreads();
    float mu = (sm[0] + sm[1] + sm[2] + sm[3]) * (1.f / 512.f);
    __syncthreads();
    float d0 = v0 - mu, d1 = v1 - mu;
    float q = wred_sum(d0 * d0 + d1 * d1);
    if ((t & 63) == 0) sm[t >> 6] = q;
    __syncthreads();
    float rstd = rsqrtf((sm[0] + sm[1] + sm[2] + sm[3]) * (1.f / 512.f) + 1e-5f);
    ln0[t] = d0 * rstd * g[t] + b[t];
    ln0[256 + t] = d1 * rstd * g[256 + t] + b[256 + t];
    __syncthreads();
    int jj = blockIdx.x * 256 + t;
    if (jj < 1000) {
        float acc = bias[jj];
        for (int dd = 0; dd < 512; ++dd) acc += ln0[dd] * W[dd * 1000 + jj];
        out[jj] = acc;
    }
}

// ================= layer driver ================================================
struct Bufs {
    float *X, *LNA, *A2, *Z0, *Z1, *XZ, *T1, *T2, *A3V, *W2, *MAXES, *SIMf;
    u16 *LNb, *Qb, *Kb, *VT, *QLb, *KLb, *W2T, *W1T, *QKVWT, *OUTWT, *SIMb;
    int g;
};

static void run_layer(hipStream_t st, Bufs& B,
                      const float* ln_g, const float* ln_b, const float* qkv_W,
                      const float* conv_W, const float* out_W, const float* out_b) {
    const int N = 16384, D = 512, H = 8, DH = 64, M = 256;
    const long HS = (long)N * DH;       // per-head q/k/v stride (bf16 elements)
    // 1. LN -> bf16
    layernorm_bf16<<<N, 256, 0, st>>>(B.X, ln_g, ln_b, B.LNb);
    // 2. qkv weights transpose + qkv gemm with split epilogue
    transpose_to_bf16<<<(512 * 1536 + 255) / 256, 256, 0, st>>>(qkv_W, B.QKVWT, 512, 1536);
    launch_mgemm<128, 128, 4>(st, B.LNb, B.QKVWT, nullptr, B.Qb, B.Kb, B.VT, nullptr,
                              0, 0, 0, N, 1536, 512, 0, 1, 1, 0);
    // 3. landmarks
    landmarks_b<<<H * M, 64, 0, st>>>(B.Qb, B.Kb, B.QLb, B.KLb);
    // 4. sim2 -> softmax -> pinv (fp32)
    launch_mgemm<128, 128, 0>(st, B.QLb, B.KLb, B.A2, nullptr, nullptr, nullptr, nullptr,
                              (long)M * DH, (long)M * DH, (long)M * M, M, M, DH, M, H, 1, 0);
    softmax_rows<<<H * M, 256, 0, st>>>(B.A2, M);
    hipMemsetAsync(B.MAXES, 0, 8, st);
    pinv_absmax<<<H, 256, 0, st>>>(B.A2, B.MAXES);
    pinv_init<<<(H * M * M) / 256, 256, 0, st>>>(B.A2, B.MAXES, B.Z0);
    float* z = B.Z0;
    float* zn = B.Z1;
    for (int it = 0; it < 6; ++it) {
        gemm32(st, M, M, M, B.A2, M, (long)M * M, z, M, (long)M * M,
               B.XZ, M, (long)M * M, H, 1.f, 0.f, 0);
        neg_diag<<<(H * M * M) / 256, 256, 0, st>>>(B.XZ, B.T1, 7.f);
        gemm32(st, M, M, M, B.XZ, M, (long)M * M, B.T1, M, (long)M * M,
               B.T2, M, (long)M * M, H, -1.f, 15.f, 0);
        gemm32(st, M, M, M, B.XZ, M, (long)M * M, B.T2, M, (long)M * M,
               B.T1, M, (long)M * M, H, -1.f, 13.f, 0);
        gemm32(st, M, M, M, z, M, (long)M * M, B.T1, M, (long)M * M,
               zn, M, (long)M * M, H, 0.25f, 0.f, 0);
        float* tmp = z; z = zn; zn = tmp;
    }
    // 5. conv residual initializes ATTN (LNA)
    conv_kernel<<<dim3(N / 64, H), 256, 0, st>>>(B.VT, conv_W, B.LNA);
    // 6. per head-group: sim3 -> softmax(bf16) -> a3v (split-K atomic)
    int g = B.g;
    for (int hg = 0; hg < H; hg += g) {
        launch_mgemm<128, 128, 0>(st, B.QLb + (long)hg * M * DH, B.Kb + (long)hg * HS,
                                  B.SIMf, nullptr, nullptr, nullptr, nullptr,
                                  (long)M * DH, HS, (long)M * N, M, N, DH, N, g, 1, 0);
        softmax_bf16<<<g * M, 256, 0, st>>>(B.SIMf, B.SIMb, N);
        hipMemsetAsync(B.A3V + (long)hg * M * DH, 0, (size_t)g * M * DH * 4, st);
        launch_mgemm<256, 64, 3>(st, B.SIMb, B.VT + (long)hg * HS,
                                 B.A3V + (long)hg * M * DH, nullptr, nullptr, nullptr, nullptr,
                                 (long)M * N, HS, (long)M * DH, M, DH, N, DH, g, 32, 0);
    }
    // 7. W2 = z @ a3v (fp32), then transpose to bf16
    gemm32(st, M, DH, M, z, M, (long)M * M, B.A3V, DH, (long)M * DH,
           B.W2, DH, (long)M * DH, H, 1.f, 0.f, 0);
    w2t_kernel<<<512, 256, 0, st>>>(B.W2, B.W2T);
    // 8. per head-group: sim1 -> softmax(bf16) -> ATTN cols += a1 @ W2
    for (int hg = 0; hg < H; hg += g) {
        launch_mgemm<128, 128, 0>(st, B.Qb + (long)hg * HS, B.KLb + (long)hg * M * DH,
                                  B.SIMf, nullptr, nullptr, nullptr, nullptr,
                                  HS, (long)M * DH, (long)N * M, N, M, DH, M, g, 1, 0);
        softmax_bf16<<<g * N, 256, 0, st>>>(B.SIMf, B.SIMb, M);
        launch_mgemm<256, 64, 5>(st, B.SIMb, B.W2T + (long)hg * DH * M, B.LNA,
                                 nullptr, nullptr, nullptr, nullptr,
                                 (long)N * M, (long)DH * M, 0, N, DH, M, D, g, 1, hg * 64);
    }
    // 9. out projection: X += ATTN @ out_W + out_b
    cvt_bf16_vec<<<(N * D / 4 + 255) / 256, 256, 0, st>>>(B.LNA, B.LNb, (long)N * D / 4);
    transpose_to_bf16<<<(512 * 512 + 255) / 256, 256, 0, st>>>(out_W, B.OUTWT, 512, 512);
    launch_mgemm<128, 128, 2>(st, B.LNb, B.OUTWT, B.X, nullptr, nullptr, nullptr, out_b,
                              0, 0, 0, N, D, D, D, 1, 1, 0);
}

extern "C" void kernel_launch(void* const* d_in, const int* in_sizes, int n_in,
                              void* d_out, int out_size, void* d_ws, size_t ws_size,
                              hipStream_t stream) {
    const float* h_in = (const float*)d_in[0];
    const float* W1 = (const float*)d_in[1];
    const float* b1 = (const float*)d_in[2];
    const float* cls = (const float*)d_in[3];
    const float* ln1_g = (const float*)d_in[4];
    const float* ln1_b = (const float*)d_in[5];
    const float* qkv1_W = (const float*)d_in[6];
    const float* conv1_W = (const float*)d_in[7];
    const float* out1_W = (const float*)d_in[8];
    const float* out1_b = (const float*)d_in[9];
    const float* ln2_g = (const float*)d_in[10];
    const float* ln2_b = (const float*)d_in[11];
    const float* qkv2_W = (const float*)d_in[12];
    const float* conv2_W = (const float*)d_in[13];
    const float* out2_W = (const float*)d_in[14];
    const float* out2_b = (const float*)d_in[15];
    const float* lnf_g = (const float*)d_in[16];
    const float* lnf_b = (const float*)d_in[17];
    const float* fc2_W = (const float*)d_in[18];
    const float* fc2_b = (const float*)d_in[19];
    float* out = (float*)d_out;

    char* wsb = (char*)d_ws;
    size_t off = 0;
    auto alloc = [&](size_t bytes) -> void* {
        void* p = (void*)(wsb + off);
        off += (bytes + 255) & ~(size_t)255;
        return p;
    };
    Bufs B;
    B.X    = (float*)alloc((size_t)16384 * 512 * 4);
    B.LNA  = (float*)alloc((size_t)16384 * 512 * 4);
    B.LNb  = (u16*)alloc((size_t)16384 * 512 * 2);
    B.Qb   = (u16*)alloc((size_t)8 * 16384 * 64 * 2);   // adjacent to Kb: HB alias
    B.Kb   = (u16*)alloc((size_t)8 * 16384 * 64 * 2);
    B.VT   = (u16*)alloc((size_t)8 * 64 * 16384 * 2);
    B.QLb  = (u16*)alloc((size_t)8 * 256 * 64 * 2);
    B.KLb  = (u16*)alloc((size_t)8 * 256 * 64 * 2);
    B.A2   = (float*)alloc((size_t)8 * 256 * 256 * 4);
    B.Z0   = (float*)alloc((size_t)8 * 256 * 256 * 4);
    B.Z1   = (float*)alloc((size_t)8 * 256 * 256 * 4);
    B.XZ   = (float*)alloc((size_t)8 * 256 * 256 * 4);
    B.T1   = (float*)alloc((size_t)8 * 256 * 256 * 4);
    B.T2   = (float*)alloc((size_t)8 * 256 * 256 * 4);
    B.A3V  = (float*)alloc((size_t)8 * 256 * 64 * 4);
    B.W2   = (float*)alloc((size_t)8 * 256 * 64 * 4);
    B.W2T  = (u16*)alloc((size_t)8 * 64 * 256 * 2);
    B.W1T  = (u16*)alloc((size_t)512 * 1024 * 2);
    B.QKVWT = (u16*)alloc((size_t)1536 * 512 * 2);
    B.OUTWT = (u16*)alloc((size_t)512 * 512 * 2);
    B.MAXES = (float*)alloc(256);
    size_t fixed = off;
    // pick largest head-group whose SIM buffers fit
    int g = 1;
    for (int cand = 8; cand >= 1; cand >>= 1) {
        size_t need = fixed + (size_t)cand * 256 * 16384 * 4 + (size_t)cand * 256 * 16384 * 2 + 4096;
        if (ws_size >= need) { g = cand; break; }
    }
    B.g = g;
    B.SIMf = (float*)alloc((size_t)g * 256 * 16384 * 4);
    B.SIMb = (u16*)alloc((size_t)g * 256 * 16384 * 2);
    if (off > ws_size) return;  // fail loudly (output stays poisoned)

    // fc1: HB (aliases Qb..Kb) = [0; h] bf16; X = relu(HB @ W1^T + b1); X[0] = cls
    u16* HB = B.Qb;
    build_hb<<<(16384 * 1024) / 256, 256, 0, stream>>>(h_in, HB);
    transpose_to_bf16<<<(1024 * 512 + 255) / 256, 256, 0, stream>>>(W1, B.W1T, 1024, 512);
    launch_mgemm<128, 128, 1>(stream, HB, B.W1T, B.X, nullptr, nullptr, nullptr, b1,
                              0, 0, 0, 16384, 512, 1024, 512, 1, 1, 0);
    cls_copy<<<1, 512, 0, stream>>>(cls, B.X);

    run_layer(stream, B, ln1_g, ln1_b, qkv1_W, conv1_W, out1_W, out1_b);
    run_layer(stream, B, ln2_g, ln2_b, qkv2_W, conv2_W, out2_W, out2_b);

    final_head<<<4, 256, 0, stream>>>(B.X, lnf_g, lnf_b, fc2_W, fc2_b, out);
}

// Round 4
// 1751.288 us; speedup vs baseline: 3.0642x; 1.5374x over previous
//
#include <hip/hip_runtime.h>
#include <math.h>

typedef unsigned short u16;
typedef short bf16x8 __attribute__((ext_vector_type(8)));
typedef float f32x4 __attribute__((ext_vector_type(4)));

__device__ __forceinline__ u16 f2b(float x) {
    unsigned u = __builtin_bit_cast(unsigned, x);
    unsigned r = u + 0x7fffu + ((u >> 16) & 1u);
    return (u16)(r >> 16);
}
__device__ __forceinline__ float b2f(u16 v) {
    return __builtin_bit_cast(float, (unsigned)v << 16);
}
__device__ __forceinline__ unsigned fenc(float x) {
    unsigned u = __builtin_bit_cast(unsigned, x);
    return (u >> 31) ? ~u : (u | 0x80000000u);
}
__device__ __forceinline__ float fdec(unsigned e) {
    unsigned u = (e >> 31) ? (e & 0x7fffffffu) : ~e;
    return __builtin_bit_cast(float, u);
}
__device__ __forceinline__ void gl_lds16(const u16* g, u16* l) {
    __builtin_amdgcn_global_load_lds(
        (const __attribute__((address_space(1))) unsigned int*)g,
        (__attribute__((address_space(3))) unsigned int*)l, 16, 0, 0);
}
__device__ __forceinline__ float wred_sum(float v) {
#pragma unroll
    for (int o = 32; o > 0; o >>= 1) v += __shfl_down(v, o, 64);
    return v;
}
__device__ __forceinline__ float wred_max(float v) {
#pragma unroll
    for (int o = 32; o > 0; o >>= 1) v = fmaxf(v, __shfl_down(v, o, 64));
    return v;
}

// ================= bf16 MFMA GEMM (NT): C[M][N] = A[M][K] @ B[N][K]^T ==========
// MODE: 0 plain fp32 C; 1 bias+relu; 2 C += acc + bias; 4 qkv-split (row-major
// q*0.125/k/v bf16); 6 bf16 C + per-row atomicMax(rowmax) [sim3 pass A]
struct GP {
    const u16* A; const u16* B; float* C;
    u16* Q; u16* Kb; u16* V;
    u16* Cb; unsigned* rmax;
    const float* bias;
    long sA, sB, sC;
    int K, ldc, tilesN;
};

template <int BM, int BN, int MODE>
__global__ __launch_bounds__(256) void mgemm(GP p) {
    constexpr int WN = BN / 64;
    constexpr int LA = BM / 64;
    constexpr int LB = BN / 64;
    __shared__ u16 As[BM * 32] __attribute__((aligned(16)));
    __shared__ u16 Bs[BN * 32] __attribute__((aligned(16)));

    int tid = threadIdx.x, lane = tid & 63, wave = tid >> 6;
    int wm = wave / WN, wn = wave % WN;
    int tm = blockIdx.x / p.tilesN, tn = blockIdx.x % p.tilesN;
    int batch = blockIdx.y;
    int m0 = tm * BM, n0 = tn * BN;
    const u16* A = p.A + (long)batch * p.sA;
    const u16* B = p.B + (long)batch * p.sB;

    f32x4 acc[4][4];
#pragma unroll
    for (int i = 0; i < 4; i++)
#pragma unroll
        for (int j = 0; j < 4; j++) acc[i][j] = (f32x4){0.f, 0.f, 0.f, 0.f};

    int lr = lane >> 2;
    int lcb = (lane & 3) << 3;
    for (int k0 = 0; k0 < p.K; k0 += 32) {
#pragma unroll
        for (int i = 0; i < LA; i++) {
            int chunk = wave * LA + i;
            gl_lds16(A + (long)(m0 + chunk * 16 + lr) * p.K + k0 + lcb,
                     As + chunk * 512 + lane * 8);
        }
#pragma unroll
        for (int i = 0; i < LB; i++) {
            int chunk = wave * LB + i;
            gl_lds16(B + (long)(n0 + chunk * 16 + lr) * p.K + k0 + lcb,
                     Bs + chunk * 512 + lane * 8);
        }
        __syncthreads();
        bf16x8 af[4], bfv[4];
        int mrow = (lane & 15), kq = (lane >> 4) * 8;
#pragma unroll
        for (int mi = 0; mi < 4; mi++)
            af[mi] = *(const bf16x8*)(As + (wm * 64 + mi * 16 + mrow) * 32 + kq);
#pragma unroll
        for (int ni = 0; ni < 4; ni++)
            bfv[ni] = *(const bf16x8*)(Bs + (wn * 64 + ni * 16 + mrow) * 32 + kq);
#pragma unroll
        for (int mi = 0; mi < 4; mi++)
#pragma unroll
            for (int ni = 0; ni < 4; ni++)
                acc[mi][ni] = __builtin_amdgcn_mfma_f32_16x16x32_bf16(
                    af[mi], bfv[ni], acc[mi][ni], 0, 0, 0);
        __syncthreads();
    }

    int quad = lane >> 4, cn = lane & 15;
    if constexpr (MODE == 6) {
        u16* Cb = p.Cb + (long)batch * p.sC;
        unsigned* rmax = p.rmax + batch * 256;
#pragma unroll
        for (int mi = 0; mi < 4; mi++) {
#pragma unroll
            for (int r = 0; r < 4; r++) {
                int row = m0 + wm * 64 + mi * 16 + quad * 4 + r;
                float vv[4];
                float mx = -1e30f;
#pragma unroll
                for (int ni = 0; ni < 4; ni++) {
                    vv[ni] = acc[mi][ni][r];
                    mx = fmaxf(mx, vv[ni]);
                }
                mx = fmaxf(mx, __shfl_xor(mx, 1));
                mx = fmaxf(mx, __shfl_xor(mx, 2));
                mx = fmaxf(mx, __shfl_xor(mx, 4));
                mx = fmaxf(mx, __shfl_xor(mx, 8));
                if (cn == 0) atomicMax(&rmax[row], fenc(mx));
#pragma unroll
                for (int ni = 0; ni < 4; ni++)
                    Cb[(long)row * p.ldc + n0 + wn * 64 + ni * 16 + cn] = f2b(vv[ni]);
            }
        }
    } else if constexpr (MODE == 4) {
#pragma unroll
        for (int mi = 0; mi < 4; mi++) {
#pragma unroll
            for (int ni = 0; ni < 4; ni++) {
#pragma unroll
                for (int r = 0; r < 4; r++) {
                    int row = m0 + wm * 64 + mi * 16 + quad * 4 + r;
                    int col = n0 + wn * 64 + ni * 16 + cn;
                    float v = acc[mi][ni][r];
                    int h = col >> 6, d = col & 63;
                    if (col < 512)
                        p.Q[((long)h * 16384 + row) * 64 + d] = f2b(v * 0.125f);
                    else if (col < 1024)
                        p.Kb[((long)(h - 8) * 16384 + row) * 64 + d] = f2b(v);
                    else
                        p.V[((long)(h - 16) * 16384 + row) * 64 + d] = f2b(v);
                }
            }
        }
    } else {
        float* C = p.C + (long)batch * p.sC;
#pragma unroll
        for (int mi = 0; mi < 4; mi++) {
#pragma unroll
            for (int ni = 0; ni < 4; ni++) {
#pragma unroll
                for (int r = 0; r < 4; r++) {
                    int row = m0 + wm * 64 + mi * 16 + quad * 4 + r;
                    int col = n0 + wn * 64 + ni * 16 + cn;
                    float v = acc[mi][ni][r];
                    if (MODE == 0) {
                        C[(long)row * p.ldc + col] = v;
                    } else if (MODE == 1) {
                        C[(long)row * p.ldc + col] = fmaxf(v + p.bias[col], 0.f);
                    } else if (MODE == 2) {
                        C[(long)row * p.ldc + col] += v + p.bias[col];
                    }
                }
            }
        }
    }
}

template <int BM, int BN, int MODE>
static void launch_mgemm(hipStream_t st, GP p, int M, int N, int batch) {
    p.tilesN = N / BN;
    dim3 grid((M / BM) * (N / BN), batch);
    mgemm<BM, BN, MODE><<<grid, 256, 0, st>>>(p);
}

// ================= sim3 pass B: a3v flash-consume ==============================
// O[head][256][64] += exp(S - m) @ V^T-tiles; l[head][256] += rowsum(exp)
__global__ __launch_bounds__(256) void a3v_flash(
    const u16* __restrict__ Sb, const u16* __restrict__ VT,
    const unsigned* __restrict__ rmax, float* __restrict__ O,
    float* __restrict__ Lsum, int hg) {
    __shared__ u16 Ss[256 * 32] __attribute__((aligned(16)));
    __shared__ u16 Vs[64 * 32] __attribute__((aligned(16)));
    int tid = threadIdx.x, lane = tid & 63, w = tid >> 6;
    int head = hg + blockIdx.y;
    const u16* S = Sb + (long)blockIdx.y * 256 * 16384;
    const u16* Vh = VT + (long)head * 64 * 16384;
    int n0 = blockIdx.x * 512;
    int quad = lane >> 4, cn = lane & 15;
    int lr = lane >> 2, lc = (lane & 3) << 3;
    float mrow[4];
#pragma unroll
    for (int mi = 0; mi < 4; mi++)
        mrow[mi] = fdec(rmax[head * 256 + w * 64 + mi * 16 + cn]);
    f32x4 acc[4][4];
#pragma unroll
    for (int i = 0; i < 4; i++)
#pragma unroll
        for (int j = 0; j < 4; j++) acc[i][j] = (f32x4){0.f, 0.f, 0.f, 0.f};
    float ladd[4] = {0.f, 0.f, 0.f, 0.f};

    for (int t = 0; t < 16; t++) {
        int c0 = n0 + t * 32;
#pragma unroll
        for (int i = 0; i < 4; i++) {
            int row = w * 64 + i * 16;
            gl_lds16(S + (long)(row + lr) * 16384 + c0 + lc, Ss + row * 32 + lane * 8);
        }
        gl_lds16(Vh + (long)(w * 16 + lr) * 16384 + c0 + lc, Vs + (w * 16) * 32 + lane * 8);
        __syncthreads();
        bf16x8 bfv[4];
#pragma unroll
        for (int ni = 0; ni < 4; ni++)
            bfv[ni] = *(const bf16x8*)(Vs + (ni * 16 + cn) * 32 + quad * 8);
#pragma unroll
        for (int mi = 0; mi < 4; mi++) {
            bf16x8 raw = *(const bf16x8*)(Ss + (w * 64 + mi * 16 + cn) * 32 + quad * 8);
            bf16x8 pf;
            float s = 0.f;
#pragma unroll
            for (int j = 0; j < 8; j++) {
                float e = expf(b2f((u16)raw[j]) - mrow[mi]);
                s += e;
                pf[j] = (short)f2b(e);
            }
            ladd[mi] += s;
#pragma unroll
            for (int ni = 0; ni < 4; ni++)
                acc[mi][ni] = __builtin_amdgcn_mfma_f32_16x16x32_bf16(
                    pf, bfv[ni], acc[mi][ni], 0, 0, 0);
        }
        __syncthreads();
    }
#pragma unroll
    for (int mi = 0; mi < 4; mi++) {
        float l = ladd[mi];
        l += __shfl_xor(l, 16);
        l += __shfl_xor(l, 32);
        if (quad == 0) atomicAdd(&Lsum[head * 256 + w * 64 + mi * 16 + cn], l);
#pragma unroll
        for (int ni = 0; ni < 4; ni++)
#pragma unroll
            for (int r = 0; r < 4; r++) {
                int row = w * 64 + mi * 16 + quad * 4 + r;
                atomicAdd(&O[((long)head * 256 + row) * 64 + ni * 16 + cn],
                          acc[mi][ni][r]);
            }
    }
}

__global__ void divide_ol(float* __restrict__ O, const float* __restrict__ L) {
    int idx = blockIdx.x * 256 + threadIdx.x;  // 8*256*64
    O[idx] = O[idx] / L[idx >> 6];
}

// ================= fused sim1 -> softmax -> @W2 ================================
__global__ __launch_bounds__(256) void attn1_fused(
    const u16* __restrict__ Qb, const u16* __restrict__ KLb,
    const u16* __restrict__ W2T, float* __restrict__ ATTN) {
    __shared__ u16 lds[32768] __attribute__((aligned(16)));
    u16* Qs = lds;             // [2][64][32]
    u16* KLs = lds + 4096;     // [2][256][32]
    u16* Ps = lds;             // [8][64][32] (after phase 1)
    u16* W2s = lds + 16384;    // [8][64][32]
    int tid = threadIdx.x, lane = tid & 63, w = tid >> 6;
    int head = blockIdx.y, n0 = blockIdx.x * 64;
    int quad = lane >> 4, cn = lane & 15;
    int lr = lane >> 2, lc = (lane & 3) << 3;
    const u16* Qh = Qb + (long)head * 16384 * 64;
    const u16* KLh = KLb + (long)head * 256 * 64;
    const u16* W2h = W2T + (long)head * 64 * 256;
#pragma unroll
    for (int c = 0; c < 2; c++)
        gl_lds16(Qh + (long)(n0 + w * 16 + lr) * 64 + c * 32 + lc,
                 Qs + c * 2048 + (w * 16) * 32 + lane * 8);
#pragma unroll
    for (int c = 0; c < 2; c++)
#pragma unroll
        for (int rg = 0; rg < 4; rg++) {
            int row = rg * 64 + w * 16;
            gl_lds16(KLh + (long)(row + lr) * 64 + c * 32 + lc,
                     KLs + c * 8192 + row * 32 + lane * 8);
        }
    __syncthreads();
    // S = Q @ KL^T : wave owns 16 rows, 256 cols
    f32x4 acc[16];
#pragma unroll
    for (int i = 0; i < 16; i++) acc[i] = (f32x4){0.f, 0.f, 0.f, 0.f};
#pragma unroll
    for (int c = 0; c < 2; c++) {
        bf16x8 af = *(const bf16x8*)(Qs + c * 2048 + (w * 16 + cn) * 32 + quad * 8);
#pragma unroll
        for (int ni = 0; ni < 16; ni++) {
            bf16x8 bfv = *(const bf16x8*)(KLs + c * 8192 + (ni * 16 + cn) * 32 + quad * 8);
            acc[ni] = __builtin_amdgcn_mfma_f32_16x16x32_bf16(af, bfv, acc[ni], 0, 0, 0);
        }
    }
    __syncthreads();  // all reads of Qs/KLs done before Ps overwrite
    // softmax rows (quad owns rows quad*4+r), write P bf16 into chunked LDS
#pragma unroll
    for (int r = 0; r < 4; r++) {
        float mx = -1e30f;
#pragma unroll
        for (int ni = 0; ni < 16; ni++) mx = fmaxf(mx, acc[ni][r]);
        mx = fmaxf(mx, __shfl_xor(mx, 1));
        mx = fmaxf(mx, __shfl_xor(mx, 2));
        mx = fmaxf(mx, __shfl_xor(mx, 4));
        mx = fmaxf(mx, __shfl_xor(mx, 8));
        float e[16];
        float s = 0.f;
#pragma unroll
        for (int ni = 0; ni < 16; ni++) {
            e[ni] = expf(acc[ni][r] - mx);
            s += e[ni];
        }
        s += __shfl_xor(s, 1);
        s += __shfl_xor(s, 2);
        s += __shfl_xor(s, 4);
        s += __shfl_xor(s, 8);
        float inv = 1.f / s;
        int prow = w * 16 + quad * 4 + r;
#pragma unroll
        for (int ni = 0; ni < 16; ni++) {
            int k = ni * 16 + cn;
            Ps[(k >> 5) * 2048 + prow * 32 + (k & 31)] = f2b(e[ni] * inv);
        }
    }
#pragma unroll
    for (int c = 0; c < 8; c++)
        gl_lds16(W2h + (long)(w * 16 + lr) * 256 + c * 32 + lc,
                 W2s + c * 2048 + (w * 16) * 32 + lane * 8);
    __syncthreads();
    // O = P @ W2 (64 cols)
    f32x4 acc2[4];
#pragma unroll
    for (int i = 0; i < 4; i++) acc2[i] = (f32x4){0.f, 0.f, 0.f, 0.f};
#pragma unroll
    for (int c = 0; c < 8; c++) {
        bf16x8 af = *(const bf16x8*)(Ps + c * 2048 + (w * 16 + cn) * 32 + quad * 8);
#pragma unroll
        for (int ni = 0; ni < 4; ni++) {
            bf16x8 bfv = *(const bf16x8*)(W2s + c * 2048 + (ni * 16 + cn) * 32 + quad * 8);
            acc2[ni] = __builtin_amdgcn_mfma_f32_16x16x32_bf16(af, bfv, acc2[ni], 0, 0, 0);
        }
    }
#pragma unroll
    for (int ni = 0; ni < 4; ni++)
#pragma unroll
        for (int r = 0; r < 4; r++) {
            int row = n0 + w * 16 + quad * 4 + r;
            ATTN[(long)row * 512 + head * 64 + ni * 16 + cn] += acc2[ni][r];
        }
}

// ================= fp32 tile GEMM (pinv xz / W2) ===============================
#define TILE 64
#define KT 16
#define LDP (TILE + 4)
__global__ __launch_bounds__(256) void gemm_kernel(
    const float* __restrict__ A, const float* __restrict__ B, float* __restrict__ C,
    int M, int N, int K, int lda, int ldb, int ldc,
    long sA, long sB, long sC, int tilesN) {
    int tm = blockIdx.x / tilesN, tn = blockIdx.x % tilesN;
    int batch = blockIdx.y;
    A += (long)batch * sA; B += (long)batch * sB; C += (long)batch * sC;
    int row0 = tm * TILE, col0 = tn * TILE;
    __shared__ float As[KT][LDP];
    __shared__ float Bs[KT][LDP];
    int t = threadIdx.x;
    int tx = t & 15, ty = t >> 4;
    float acc[4][4] = {{0.f}};
    int aRow = t >> 2, aK = (t & 3) << 2;
    int bN = t & 63, bK = (t >> 6) << 2;
    for (int k0 = 0; k0 < K; k0 += KT) {
        {
            int r = row0 + aRow;
            float4 av = make_float4(0.f, 0.f, 0.f, 0.f);
            if (r < M) av = *(const float4*)(A + (long)r * lda + k0 + aK);
            As[aK][aRow] = av.x; As[aK + 1][aRow] = av.y;
            As[aK + 2][aRow] = av.z; As[aK + 3][aRow] = av.w;
        }
        {
            const float* bp = B + (long)(k0 + bK) * ldb + col0 + bN;
            bool ok = col0 + bN < N;
#pragma unroll
            for (int j = 0; j < 4; j++) Bs[bK + j][bN] = ok ? bp[(long)j * ldb] : 0.f;
        }
        __syncthreads();
#pragma unroll
        for (int kk = 0; kk < KT; kk++) {
            float4 a = *(const float4*)&As[kk][ty << 2];
            float4 b = *(const float4*)&Bs[kk][tx << 2];
            acc[0][0] += a.x * b.x; acc[0][1] += a.x * b.y; acc[0][2] += a.x * b.z; acc[0][3] += a.x * b.w;
            acc[1][0] += a.y * b.x; acc[1][1] += a.y * b.y; acc[1][2] += a.y * b.z; acc[1][3] += a.y * b.w;
            acc[2][0] += a.z * b.x; acc[2][1] += a.z * b.y; acc[2][2] += a.z * b.z; acc[2][3] += a.z * b.w;
            acc[3][0] += a.w * b.x; acc[3][1] += a.w * b.y; acc[3][2] += a.w * b.z; acc[3][3] += a.w * b.w;
        }
        __syncthreads();
    }
#pragma unroll
    for (int i = 0; i < 4; i++) {
        int row = row0 + (ty << 2) + i;
        if (row >= M) continue;
        float* cp = C + (long)row * ldc + col0 + (tx << 2);
#pragma unroll
        for (int j = 0; j < 4; j++) {
            int col = col0 + (tx << 2) + j;
            if (col >= N) continue;
            cp[j] = acc[i][j];
        }
    }
}
static void gemm32(hipStream_t st, int M, int N, int K,
                   const float* A, int lda, long sA,
                   const float* B, int ldb, long sB,
                   float* C, int ldc, long sC, int batch) {
    int tilesM = (M + TILE - 1) / TILE, tilesN = (N + TILE - 1) / TILE;
    dim3 grid(tilesM * tilesN, batch);
    gemm_kernel<<<grid, 256, 0, st>>>(A, B, C, M, N, K, lda, ldb, ldc, sA, sB, sC, tilesN);
}

// ================= pinv fused chain: zn = 0.25 z(13I - xz(15I - xz(7I - xz))) ==
// column-local: grid (32 col-blocks of 8, 8 heads)
__global__ __launch_bounds__(256) void pinv_chain(const float* __restrict__ xz,
                                                  const float* __restrict__ z,
                                                  float* __restrict__ zn) {
    int h = blockIdx.y, c0 = blockIdx.x * 8;
    const float* X = xz + (long)h * 65536;
    const float* Z = z + (long)h * 65536;
    __shared__ float ta[256][8];
    __shared__ float tb[256][8];
    int t = threadIdx.x;
    const float4* X4 = (const float4*)(X + t * 256);
    const float4* Z4 = (const float4*)(Z + t * 256);
    float acc[8];
#pragma unroll
    for (int j = 0; j < 8; j++)
        ta[t][j] = ((t == c0 + j) ? 7.f : 0.f) - X[t * 256 + c0 + j];
    __syncthreads();
    // tb = 15I - X@ta
#pragma unroll
    for (int j = 0; j < 8; j++) acc[j] = 0.f;
    for (int k4 = 0; k4 < 64; k4++) {
        float4 xv = X4[k4];
#pragma unroll
        for (int j = 0; j < 8; j++)
            acc[j] += xv.x * ta[k4 * 4][j] + xv.y * ta[k4 * 4 + 1][j] +
                      xv.z * ta[k4 * 4 + 2][j] + xv.w * ta[k4 * 4 + 3][j];
    }
#pragma unroll
    for (int j = 0; j < 8; j++)
        tb[t][j] = ((t == c0 + j) ? 15.f : 0.f) - acc[j];
    __syncthreads();
    // ta = 13I - X@tb
#pragma unroll
    for (int j = 0; j < 8; j++) acc[j] = 0.f;
    for (int k4 = 0; k4 < 64; k4++) {
        float4 xv = X4[k4];
#pragma unroll
        for (int j = 0; j < 8; j++)
            acc[j] += xv.x * tb[k4 * 4][j] + xv.y * tb[k4 * 4 + 1][j] +
                      xv.z * tb[k4 * 4 + 2][j] + xv.w * tb[k4 * 4 + 3][j];
    }
    __syncthreads();
#pragma unroll
    for (int j = 0; j < 8; j++)
        ta[t][j] = ((t == c0 + j) ? 13.f : 0.f) - acc[j];
    __syncthreads();
    // zn = 0.25 * Z@ta
#pragma unroll
    for (int j = 0; j < 8; j++) acc[j] = 0.f;
    for (int k4 = 0; k4 < 64; k4++) {
        float4 zv = Z4[k4];
#pragma unroll
        for (int j = 0; j < 8; j++)
            acc[j] += zv.x * ta[k4 * 4][j] + zv.y * ta[k4 * 4 + 1][j] +
                      zv.z * ta[k4 * 4 + 2][j] + zv.w * ta[k4 * 4 + 3][j];
    }
#pragma unroll
    for (int j = 0; j < 8; j++)
        zn[(long)h * 65536 + t * 256 + c0 + j] = 0.25f * acc[j];
}

// ================= layernorm / softmax / misc =================================
__global__ __launch_bounds__(256) void layernorm_bf16(
    const float* __restrict__ x, const float* __restrict__ g,
    const float* __restrict__ b, u16* __restrict__ y) {
    __shared__ float sm[4];
    long base = (long)blockIdx.x * 512;
    int t = threadIdx.x;
    float v0 = x[base + t], v1 = x[base + 256 + t];
    float s = wred_sum(v0 + v1);
    if ((t & 63) == 0) sm[t >> 6] = s;
    __syncthreads();
    float mu = (sm[0] + sm[1] + sm[2] + sm[3]) * (1.f / 512.f);
    __syncthreads();
    float d0 = v0 - mu, d1 = v1 - mu;
    float q = wred_sum(d0 * d0 + d1 * d1);
    if ((t & 63) == 0) sm[t >> 6] = q;
    __syncthreads();
    float var = (sm[0] + sm[1] + sm[2] + sm[3]) * (1.f / 512.f);
    float rstd = rsqrtf(var + 1e-5f);
    y[base + t] = f2b(d0 * rstd * g[t] + b[t]);
    y[base + 256 + t] = f2b(d1 * rstd * g[256 + t] + b[256 + t]);
}

__global__ __launch_bounds__(256) void softmax_rows(float* __restrict__ data, int ncols) {
    __shared__ float sm[4];
    float* row = data + (long)blockIdx.x * ncols;
    int t = threadIdx.x;
    float m = -1e30f;
    for (int c = t; c < ncols; c += 256) m = fmaxf(m, row[c]);
    m = wred_max(m);
    if ((t & 63) == 0) sm[t >> 6] = m;
    __syncthreads();
    m = fmaxf(fmaxf(sm[0], sm[1]), fmaxf(sm[2], sm[3]));
    __syncthreads();
    float s = 0.f;
    for (int c = t; c < ncols; c += 256) {
        float e = expf(row[c] - m);
        row[c] = e;
        s += e;
    }
    s = wred_sum(s);
    if ((t & 63) == 0) sm[t >> 6] = s;
    __syncthreads();
    s = sm[0] + sm[1] + sm[2] + sm[3];
    float inv = 1.f / s;
    for (int c = t; c < ncols; c += 256) row[c] *= inv;
}

__global__ void cls_copy(const float* __restrict__ cls, float* __restrict__ X) {
    X[threadIdx.x] = cls[threadIdx.x];
}
__global__ void build_hb(const float* __restrict__ h, u16* __restrict__ dst) {
    long idx = (long)blockIdx.x * 256 + threadIdx.x;
    long row = idx >> 10;
    int col = (int)(idx & 1023);
    float v = (row == 0) ? 0.f : h[((row - 1) << 10) + col];
    dst[idx] = f2b(v);
}
__global__ void transpose_to_bf16(const float* __restrict__ src, u16* __restrict__ dst,
                                  int R, int C) {
    long idx = (long)blockIdx.x * 256 + threadIdx.x;
    if (idx >= (long)R * C) return;
    int r = (int)(idx / C), c = (int)(idx % C);
    dst[(long)c * R + r] = f2b(src[idx]);
}
__global__ void cvt_bf16_vec(const float* __restrict__ src, u16* __restrict__ dst, long n4) {
    long i = (long)blockIdx.x * 256 + threadIdx.x;
    if (i >= n4) return;
    float4 v = ((const float4*)src)[i];
    union { u16 h[4]; uint2 u; } o;
    o.h[0] = f2b(v.x); o.h[1] = f2b(v.y); o.h[2] = f2b(v.z); o.h[3] = f2b(v.w);
    ((uint2*)dst)[i] = o.u;
}
__global__ __launch_bounds__(256) void transpose_v(const u16* __restrict__ Vb,
                                                   u16* __restrict__ VT) {
    __shared__ u16 tile[64][68];
    int h = blockIdx.y, n0 = blockIdx.x * 64;
    int t = threadIdx.x;
    int i = t >> 2, seg = t & 3;
    const u16* src = Vb + ((long)h * 16384 + n0 + i) * 64 + seg * 16;
#pragma unroll
    for (int j = 0; j < 16; j++) tile[seg * 16 + j][i] = src[j];
    __syncthreads();
    u16* dst = VT + ((long)h * 64 + i) * 16384 + n0 + seg * 16;
#pragma unroll
    for (int j = 0; j < 16; j++) dst[j] = tile[i][seg * 16 + j];
}
__global__ void landmarks_b(const u16* __restrict__ Qb, const u16* __restrict__ Kb,
                            u16* __restrict__ QLb, u16* __restrict__ KLb) {
    int h = blockIdx.x >> 8, j = blockIdx.x & 255, d = threadIdx.x;
    const u16* qb = Qb + ((long)h * 16384 + j * 64) * 64 + d;
    const u16* kb = Kb + ((long)h * 16384 + j * 64) * 64 + d;
    float sq = 0.f, sk = 0.f;
    for (int tk = 0; tk < 64; ++tk) {
        sq += b2f(qb[tk * 64]);
        sk += b2f(kb[tk * 64]);
    }
    QLb[((h << 8) + j) * 64 + d] = f2b(sq * (1.f / 64.f));
    KLb[((h << 8) + j) * 64 + d] = f2b(sk * (1.f / 64.f));
}
__global__ __launch_bounds__(256) void pinv_absmax(const float* __restrict__ a2,
                                                   float* __restrict__ maxes) {
    __shared__ float sm[4];
    const float* Xh = a2 + (long)blockIdx.x * 65536;
    int t = threadIdx.x;
    float cs = 0.f, rs = 0.f;
    for (int j = 0; j < 256; j++) {
        cs += fabsf(Xh[t * 256 + j]);
        rs += fabsf(Xh[j * 256 + t]);
    }
    float cm = wred_max(cs);
    if ((t & 63) == 0) sm[t >> 6] = cm;
    __syncthreads();
    cm = fmaxf(fmaxf(sm[0], sm[1]), fmaxf(sm[2], sm[3]));
    if (t == 0) atomicMax((int*)&maxes[0], __float_as_int(cm));
    __syncthreads();
    float rm = wred_max(rs);
    if ((t & 63) == 0) sm[t >> 6] = rm;
    __syncthreads();
    rm = fmaxf(fmaxf(sm[0], sm[1]), fmaxf(sm[2], sm[3]));
    if (t == 0) atomicMax((int*)&maxes[1], __float_as_int(rm));
}
__global__ void pinv_init(const float* __restrict__ a2, const float* __restrict__ maxes,
                          float* __restrict__ z) {
    long idx = (long)blockIdx.x * 256 + threadIdx.x;
    int h = (int)(idx >> 16);
    int rem = (int)(idx & 65535);
    int i = rem >> 8, j = rem & 255;
    float inv = 1.f / (maxes[0] * maxes[1]);
    z[idx] = a2[((long)h << 16) + (j << 8) + i] * inv;
}
__global__ __launch_bounds__(256) void conv_kernel(const u16* __restrict__ VT,
                                                   const float* __restrict__ cw,
                                                   float* __restrict__ out) {
    int h = blockIdx.y;
    int n0 = blockIdx.x * 64;
    __shared__ float vt[64][97];
    int t = threadIdx.x;
    for (int i = t; i < 64 * 96; i += 256) {
        int d = i / 96, j = i % 96;
        int n = n0 - 16 + j;
        float v = 0.f;
        if (n >= 0 && n < 16384) v = b2f(VT[((long)h * 64 + d) * 16384 + n]);
        vt[d][j] = v;
    }
    __syncthreads();
    float w[33];
#pragma unroll
    for (int k = 0; k < 33; k++) w[k] = cw[h * 33 + k];
    int d = t & 63, ty = t >> 6;
    for (int nn = 0; nn < 16; nn++) {
        int nl = ty * 16 + nn;
        float s = 0.f;
#pragma unroll
        for (int k = 0; k < 33; k++) s += w[k] * vt[d][nl + k];
        out[((long)(n0 + nl)) * 512 + h * 64 + d] = s;
    }
}
__global__ void w2t_kernel(const float* __restrict__ W2, u16* __restrict__ W2T) {
    int idx = blockIdx.x * 256 + threadIdx.x;  // 8*256*64
    int h = idx >> 14, rem = idx & 16383, m = rem >> 6, d = rem & 63;
    W2T[(h << 14) + (d << 8) + m] = f2b(W2[idx]);
}
__global__ __launch_bounds__(256) void final_head(
    const float* __restrict__ X, const float* __restrict__ g, const float* __restrict__ b,
    const float* __restrict__ W, const float* __restrict__ bias, float* __restrict__ out) {
    __shared__ float sm[4];
    __shared__ float ln0[512];
    int t = threadIdx.x;
    float v0 = X[t], v1 = X[256 + t];
    float s = wred_sum(v0 + v1);
    if ((t & 63) == 0) sm[t >> 6] = s;
    __syncthreads();
    float mu = (sm[0] + sm[1] + sm[2] + sm[3]) * (1.f / 512.f);
    __syncthreads();
    float d0 = v0 - mu, d1 = v1 - mu;
    float q = wred_sum(d0 * d0 + d1 * d1);
    if ((t & 63) == 0) sm[t >> 6] = q;
    __syncthreads();
    float rstd = rsqrtf((sm[0] + sm[1] + sm[2] + sm[3]) * (1.f / 512.f) + 1e-5f);
    ln0[t] = d0 * rstd * g[t] + b[t];
    ln0[256 + t] = d1 * rstd * g[256 + t] + b[256 + t];
    __syncthreads();
    int jj = blockIdx.x * 256 + t;
    if (jj < 1000) {
        float acc = bias[jj];
        for (int dd = 0; dd < 512; ++dd) acc += ln0[dd] * W[dd * 1000 + jj];
        out[jj] = acc;
    }
}

// ================= layer driver ================================================
struct Bufs {
    float *X, *LNA, *A2, *Z0, *Z1, *XZ, *O, *Lsum, *W2, *MAXES;
    u16 *LNb, *Qb, *Kb, *Vb, *VT, *QLb, *KLb, *W2T, *W1T, *QKVWT, *OUTWT, *Sb;
    unsigned* RMAX;
    int g;
};

static void run_layer(hipStream_t st, Bufs& B,
                      const float* ln_g, const float* ln_b, const float* qkv_W,
                      const float* conv_W, const float* out_W, const float* out_b) {
    const int N = 16384, D = 512, H = 8, DH = 64, M = 256;
    const long HS = (long)N * DH;
    GP p{};
    // 1. LN -> bf16
    layernorm_bf16<<<N, 256, 0, st>>>(B.X, ln_g, ln_b, B.LNb);
    // 2. qkv (row-major q/k/v epilogue), then VT transpose
    transpose_to_bf16<<<(512 * 1536 + 255) / 256, 256, 0, st>>>(qkv_W, B.QKVWT, 512, 1536);
    p = GP{}; p.A = B.LNb; p.B = B.QKVWT; p.Q = B.Qb; p.Kb = B.Kb; p.V = B.Vb; p.K = 512;
    launch_mgemm<128, 128, 4>(st, p, N, 1536, 1);
    transpose_v<<<dim3(256, 8), 256, 0, st>>>(B.Vb, B.VT);
    // 3. landmarks
    landmarks_b<<<H * M, 64, 0, st>>>(B.Qb, B.Kb, B.QLb, B.KLb);
    // 4. sim2 -> softmax -> pinv
    p = GP{}; p.A = B.QLb; p.B = B.KLb; p.C = B.A2; p.K = DH; p.ldc = M;
    p.sA = (long)M * DH; p.sB = (long)M * DH; p.sC = (long)M * M;
    launch_mgemm<128, 128, 0>(st, p, M, M, H);
    softmax_rows<<<H * M, 256, 0, st>>>(B.A2, M);
    hipMemsetAsync(B.MAXES, 0, 8, st);
    pinv_absmax<<<H, 256, 0, st>>>(B.A2, B.MAXES);
    pinv_init<<<(H * M * M) / 256, 256, 0, st>>>(B.A2, B.MAXES, B.Z0);
    float* z = B.Z0;
    float* zn = B.Z1;
    for (int it = 0; it < 6; ++it) {
        gemm32(st, M, M, M, B.A2, M, (long)M * M, z, M, (long)M * M,
               B.XZ, M, (long)M * M, H);
        pinv_chain<<<dim3(32, 8), 256, 0, st>>>(B.XZ, z, zn);
        float* tmp = z; z = zn; zn = tmp;
    }
    // 5. conv residual initializes ATTN (LNA)
    conv_kernel<<<dim3(N / 64, H), 256, 0, st>>>(B.VT, conv_W, B.LNA);
    // 6. sim3 pass A (bf16 S + rowmax) / pass B (flash consume) per head-group
    hipMemsetAsync(B.RMAX, 0, H * M * 4, st);
    hipMemsetAsync(B.O, 0, (size_t)H * M * DH * 4, st);
    hipMemsetAsync(B.Lsum, 0, H * M * 4, st);
    int g = B.g;
    for (int hg = 0; hg < H; hg += g) {
        p = GP{}; p.A = B.QLb + (long)hg * M * DH; p.B = B.Kb + (long)hg * HS;
        p.Cb = B.Sb; p.rmax = B.RMAX + hg * 256; p.K = DH; p.ldc = N;
        p.sA = (long)M * DH; p.sB = HS; p.sC = (long)M * N;
        launch_mgemm<128, 128, 6>(st, p, M, N, g);
        a3v_flash<<<dim3(32, g), 256, 0, st>>>(B.Sb, B.VT, B.RMAX, B.O, B.Lsum, hg);
    }
    divide_ol<<<(H * M * DH) / 256, 256, 0, st>>>(B.O, B.Lsum);
    // 7. W2 = z @ a3v (fp32), transpose to bf16
    gemm32(st, M, DH, M, z, M, (long)M * M, B.O, DH, (long)M * DH,
           B.W2, DH, (long)M * DH, H);
    w2t_kernel<<<512, 256, 0, st>>>(B.W2, B.W2T);
    // 8. fused sim1 -> softmax -> @W2 into ATTN
    attn1_fused<<<dim3(N / 64, H), 256, 0, st>>>(B.Qb, B.KLb, B.W2T, B.LNA);
    // 9. out projection: X += ATTN @ out_W + out_b
    cvt_bf16_vec<<<(N * D / 4 + 255) / 256, 256, 0, st>>>(B.LNA, B.LNb, (long)N * D / 4);
    transpose_to_bf16<<<(512 * 512 + 255) / 256, 256, 0, st>>>(out_W, B.OUTWT, 512, 512);
    p = GP{}; p.A = B.LNb; p.B = B.OUTWT; p.C = B.X; p.bias = out_b; p.K = D; p.ldc = D;
    launch_mgemm<128, 128, 2>(st, p, N, D, 1);
}

extern "C" void kernel_launch(void* const* d_in, const int* in_sizes, int n_in,
                              void* d_out, int out_size, void* d_ws, size_t ws_size,
                              hipStream_t stream) {
    const float* h_in = (const float*)d_in[0];
    const float* W1 = (const float*)d_in[1];
    const float* b1 = (const float*)d_in[2];
    const float* cls = (const float*)d_in[3];
    const float* ln1_g = (const float*)d_in[4];
    const float* ln1_b = (const float*)d_in[5];
    const float* qkv1_W = (const float*)d_in[6];
    const float* conv1_W = (const float*)d_in[7];
    const float* out1_W = (const float*)d_in[8];
    const float* out1_b = (const float*)d_in[9];
    const float* ln2_g = (const float*)d_in[10];
    const float* ln2_b = (const float*)d_in[11];
    const float* qkv2_W = (const float*)d_in[12];
    const float* conv2_W = (const float*)d_in[13];
    const float* out2_W = (const float*)d_in[14];
    const float* out2_b = (const float*)d_in[15];
    const float* lnf_g = (const float*)d_in[16];
    const float* lnf_b = (const float*)d_in[17];
    const float* fc2_W = (const float*)d_in[18];
    const float* fc2_b = (const float*)d_in[19];
    float* out = (float*)d_out;

    char* wsb = (char*)d_ws;
    size_t off = 0;
    auto alloc = [&](size_t bytes) -> void* {
        void* p = (void*)(wsb + off);
        off += (bytes + 255) & ~(size_t)255;
        return p;
    };
    Bufs B;
    B.X    = (float*)alloc((size_t)16384 * 512 * 4);
    B.LNA  = (float*)alloc((size_t)16384 * 512 * 4);
    B.LNb  = (u16*)alloc((size_t)16384 * 512 * 2);
    B.Qb   = (u16*)alloc((size_t)8 * 16384 * 64 * 2);   // adjacent to Kb: HB alias
    B.Kb   = (u16*)alloc((size_t)8 * 16384 * 64 * 2);
    B.VT   = (u16*)alloc((size_t)8 * 64 * 16384 * 2);
    B.QLb  = (u16*)alloc((size_t)8 * 256 * 64 * 2);
    B.KLb  = (u16*)alloc((size_t)8 * 256 * 64 * 2);
    B.A2   = (float*)alloc((size_t)8 * 256 * 256 * 4);
    B.Z0   = (float*)alloc((size_t)8 * 256 * 256 * 4);
    B.Z1   = (float*)alloc((size_t)8 * 256 * 256 * 4);
    B.XZ   = (float*)alloc((size_t)8 * 256 * 256 * 4);
    B.O    = (float*)alloc((size_t)8 * 256 * 64 * 4);
    B.Lsum = (float*)alloc((size_t)8 * 256 * 4);
    B.RMAX = (unsigned*)alloc((size_t)8 * 256 * 4);
    B.W2   = (float*)alloc((size_t)8 * 256 * 64 * 4);
    B.W2T  = (u16*)alloc((size_t)8 * 64 * 256 * 2);
    B.W1T  = (u16*)alloc((size_t)512 * 1024 * 2);
    B.QKVWT = (u16*)alloc((size_t)1536 * 512 * 2);
    B.OUTWT = (u16*)alloc((size_t)512 * 512 * 2);
    B.MAXES = (float*)alloc(256);
    size_t fixed = off;
    // union region: Vb (16 MB, dead after transpose_v) aliases Sb (g*8 MB)
    int g = 1;
    for (int cand = 8; cand >= 1; cand >>= 1) {
        size_t uni = (size_t)cand * 256 * 16384 * 2;
        if (uni < (size_t)16 * 1024 * 1024) uni = (size_t)16 * 1024 * 1024;
        if (ws_size >= fixed + uni + 4096) { g = cand; break; }
    }
    B.g = g;
    {
        size_t uni = (size_t)g * 256 * 16384 * 2;
        if (uni < (size_t)16 * 1024 * 1024) uni = (size_t)16 * 1024 * 1024;
        void* region = alloc(uni);
        B.Vb = (u16*)region;
        B.Sb = (u16*)region;
    }
    if (off > ws_size) return;  // fail loudly (output stays poisoned)

    // fc1: HB (aliases Qb..Kb, 32MB) = [0; h] bf16; X = relu(HB @ W1^T + b1); X[0]=cls
    u16* HB = B.Qb;
    build_hb<<<(16384 * 1024) / 256, 256, 0, stream>>>(h_in, HB);
    transpose_to_bf16<<<(1024 * 512 + 255) / 256, 256, 0, stream>>>(W1, B.W1T, 1024, 512);
    {
        GP p{}; p.A = HB; p.B = B.W1T; p.C = B.X; p.bias = b1; p.K = 1024; p.ldc = 512;
        launch_mgemm<128, 128, 1>(stream, p, 16384, 512, 1);
    }
    cls_copy<<<1, 512, 0, stream>>>(cls, B.X);

    run_layer(stream, B, ln1_g, ln1_b, qkv1_W, conv1_W, out1_W, out1_b);
    run_layer(stream, B, ln2_g, ln2_b, qkv2_W, conv2_W, out2_W, out2_b);

    final_head<<<4, 256, 0, stream>>>(B.X, lnf_g, lnf_b, fc2_W, fc2_b, out);
}

// Round 5
// 1652.123 us; speedup vs baseline: 3.2481x; 1.0600x over previous
//
#include <hip/hip_runtime.h>
#include <math.h>

typedef unsigned short u16;
typedef short bf16x8 __attribute__((ext_vector_type(8)));
typedef float f32x4 __attribute__((ext_vector_type(4)));

__device__ __forceinline__ u16 f2b(float x) {
    unsigned u = __builtin_bit_cast(unsigned, x);
    unsigned r = u + 0x7fffu + ((u >> 16) & 1u);
    return (u16)(r >> 16);
}
__device__ __forceinline__ float b2f(u16 v) {
    return __builtin_bit_cast(float, (unsigned)v << 16);
}
__device__ __forceinline__ unsigned fenc(float x) {
    unsigned u = __builtin_bit_cast(unsigned, x);
    return (u >> 31) ? ~u : (u | 0x80000000u);
}
__device__ __forceinline__ float fdec(unsigned e) {
    unsigned u = (e >> 31) ? (e & 0x7fffffffu) : ~e;
    return __builtin_bit_cast(float, u);
}
__device__ __forceinline__ void gl_lds16(const u16* g, u16* l) {
    __builtin_amdgcn_global_load_lds(
        (const __attribute__((address_space(1))) unsigned int*)g,
        (__attribute__((address_space(3))) unsigned int*)l, 16, 0, 0);
}
__device__ __forceinline__ float wred_sum(float v) {
#pragma unroll
    for (int o = 32; o > 0; o >>= 1) v += __shfl_down(v, o, 64);
    return v;
}
__device__ __forceinline__ float wred_max(float v) {
#pragma unroll
    for (int o = 32; o > 0; o >>= 1) v = fmaxf(v, __shfl_down(v, o, 64));
    return v;
}

// ================= bf16 MFMA GEMM (NT): C[M][N] = A[M][K] @ B[N][K]^T ==========
// LDS chunk layout = [4 ksegs][16 rows][8] (conflict-free ds_read_b128:
// lane assignment r=lane&15, s=lane>>4 keeps dst=base+lane*16B; fragment read
// at quad*128 + mrow*8 is 16 lanes x 16B contiguous).
// MODE: 0 plain fp32 C; 1 bias+relu; 2 C += acc + bias; 4 qkv-split (row-major
// q*0.125/k/v bf16); 6 bf16 C + per-row atomicMax(rowmax) [sim3 pass A]
struct GP {
    const u16* A; const u16* B; float* C;
    u16* Q; u16* Kb; u16* V;
    u16* Cb; unsigned* rmax;
    const float* bias;
    long sA, sB, sC;
    int K, ldc, tilesN;
};

template <int BM, int BN, int MODE>
__global__ __launch_bounds__(256) void mgemm(GP p) {
    constexpr int WN = BN / 64;
    constexpr int LA = BM / 64;
    constexpr int LB = BN / 64;
    __shared__ u16 As[BM * 32] __attribute__((aligned(16)));
    __shared__ u16 Bs[BN * 32] __attribute__((aligned(16)));

    int tid = threadIdx.x, lane = tid & 63, wave = tid >> 6;
    int wm = wave / WN, wn = wave % WN;
    int tm = blockIdx.x / p.tilesN, tn = blockIdx.x % p.tilesN;
    int batch = blockIdx.y;
    int m0 = tm * BM, n0 = tn * BN;
    const u16* A = p.A + (long)batch * p.sA;
    const u16* B = p.B + (long)batch * p.sB;

    f32x4 acc[4][4];
#pragma unroll
    for (int i = 0; i < 4; i++)
#pragma unroll
        for (int j = 0; j < 4; j++) acc[i][j] = (f32x4){0.f, 0.f, 0.f, 0.f};

    int lr = lane & 15;              // row within 16-row chunk
    int lcb = (lane >> 4) << 3;      // k-seg element offset
    int quad = lane >> 4, cn = lane & 15;
    for (int k0 = 0; k0 < p.K; k0 += 32) {
#pragma unroll
        for (int i = 0; i < LA; i++) {
            int chunk = wave * LA + i;
            gl_lds16(A + (long)(m0 + chunk * 16 + lr) * p.K + k0 + lcb,
                     As + chunk * 512 + lane * 8);
        }
#pragma unroll
        for (int i = 0; i < LB; i++) {
            int chunk = wave * LB + i;
            gl_lds16(B + (long)(n0 + chunk * 16 + lr) * p.K + k0 + lcb,
                     Bs + chunk * 512 + lane * 8);
        }
        __syncthreads();
        bf16x8 af[4], bfv[4];
#pragma unroll
        for (int mi = 0; mi < 4; mi++)
            af[mi] = *(const bf16x8*)(As + (wm * 4 + mi) * 512 + quad * 128 + cn * 8);
#pragma unroll
        for (int ni = 0; ni < 4; ni++)
            bfv[ni] = *(const bf16x8*)(Bs + (wn * 4 + ni) * 512 + quad * 128 + cn * 8);
#pragma unroll
        for (int mi = 0; mi < 4; mi++)
#pragma unroll
            for (int ni = 0; ni < 4; ni++)
                acc[mi][ni] = __builtin_amdgcn_mfma_f32_16x16x32_bf16(
                    af[mi], bfv[ni], acc[mi][ni], 0, 0, 0);
        __syncthreads();
    }

    if constexpr (MODE == 6) {
        u16* Cb = p.Cb + (long)batch * p.sC;
        unsigned* rmax = p.rmax + batch * 256;
#pragma unroll
        for (int mi = 0; mi < 4; mi++) {
#pragma unroll
            for (int r = 0; r < 4; r++) {
                int row = m0 + wm * 64 + mi * 16 + quad * 4 + r;
                float vv[4];
                float mx = -1e30f;
#pragma unroll
                for (int ni = 0; ni < 4; ni++) {
                    vv[ni] = acc[mi][ni][r];
                    mx = fmaxf(mx, vv[ni]);
                }
                mx = fmaxf(mx, __shfl_xor(mx, 1));
                mx = fmaxf(mx, __shfl_xor(mx, 2));
                mx = fmaxf(mx, __shfl_xor(mx, 4));
                mx = fmaxf(mx, __shfl_xor(mx, 8));
                if (cn == 0) atomicMax(&rmax[row], fenc(mx));
#pragma unroll
                for (int ni = 0; ni < 4; ni++)
                    Cb[(long)row * p.ldc + n0 + wn * 64 + ni * 16 + cn] = f2b(vv[ni]);
            }
        }
    } else if constexpr (MODE == 4) {
#pragma unroll
        for (int mi = 0; mi < 4; mi++) {
#pragma unroll
            for (int ni = 0; ni < 4; ni++) {
#pragma unroll
                for (int r = 0; r < 4; r++) {
                    int row = m0 + wm * 64 + mi * 16 + quad * 4 + r;
                    int col = n0 + wn * 64 + ni * 16 + cn;
                    float v = acc[mi][ni][r];
                    int h = col >> 6, d = col & 63;
                    if (col < 512)
                        p.Q[((long)h * 16384 + row) * 64 + d] = f2b(v * 0.125f);
                    else if (col < 1024)
                        p.Kb[((long)(h - 8) * 16384 + row) * 64 + d] = f2b(v);
                    else
                        p.V[((long)(h - 16) * 16384 + row) * 64 + d] = f2b(v);
                }
            }
        }
    } else {
        float* C = p.C + (long)batch * p.sC;
#pragma unroll
        for (int mi = 0; mi < 4; mi++) {
#pragma unroll
            for (int ni = 0; ni < 4; ni++) {
#pragma unroll
                for (int r = 0; r < 4; r++) {
                    int row = m0 + wm * 64 + mi * 16 + quad * 4 + r;
                    int col = n0 + wn * 64 + ni * 16 + cn;
                    float v = acc[mi][ni][r];
                    if (MODE == 0) {
                        C[(long)row * p.ldc + col] = v;
                    } else if (MODE == 1) {
                        C[(long)row * p.ldc + col] = fmaxf(v + p.bias[col], 0.f);
                    } else if (MODE == 2) {
                        C[(long)row * p.ldc + col] += v + p.bias[col];
                    }
                }
            }
        }
    }
}

template <int BM, int BN, int MODE>
static void launch_mgemm(hipStream_t st, GP p, int M, int N, int batch) {
    p.tilesN = N / BN;
    dim3 grid((M / BM) * (N / BN), batch);
    mgemm<BM, BN, MODE><<<grid, 256, 0, st>>>(p);
}

// ================= sim3 pass B: a3v flash-consume ==============================
__global__ __launch_bounds__(256) void a3v_flash(
    const u16* __restrict__ Sb, const u16* __restrict__ VT,
    const unsigned* __restrict__ rmax, float* __restrict__ O,
    float* __restrict__ Lsum, int hg) {
    __shared__ u16 Ss[256 * 32] __attribute__((aligned(16)));
    __shared__ u16 Vs[64 * 32] __attribute__((aligned(16)));
    int tid = threadIdx.x, lane = tid & 63, w = tid >> 6;
    int head = hg + blockIdx.y;
    const u16* S = Sb + (long)blockIdx.y * 256 * 16384;
    const u16* Vh = VT + (long)head * 64 * 16384;
    int n0 = blockIdx.x * 512;
    int quad = lane >> 4, cn = lane & 15;
    int lr = lane & 15, lc = (lane >> 4) << 3;
    float mrow[4];
#pragma unroll
    for (int mi = 0; mi < 4; mi++)
        mrow[mi] = fdec(rmax[head * 256 + w * 64 + mi * 16 + cn]);
    f32x4 acc[4][4];
#pragma unroll
    for (int i = 0; i < 4; i++)
#pragma unroll
        for (int j = 0; j < 4; j++) acc[i][j] = (f32x4){0.f, 0.f, 0.f, 0.f};
    float ladd[4] = {0.f, 0.f, 0.f, 0.f};

    for (int t = 0; t < 16; t++) {
        int c0 = n0 + t * 32;
#pragma unroll
        for (int i = 0; i < 4; i++) {
            int chunk = w * 4 + i;
            gl_lds16(S + (long)(chunk * 16 + lr) * 16384 + c0 + lc,
                     Ss + chunk * 512 + lane * 8);
        }
        gl_lds16(Vh + (long)(w * 16 + lr) * 16384 + c0 + lc, Vs + w * 512 + lane * 8);
        __syncthreads();
        bf16x8 bfv[4];
#pragma unroll
        for (int ni = 0; ni < 4; ni++)
            bfv[ni] = *(const bf16x8*)(Vs + ni * 512 + quad * 128 + cn * 8);
#pragma unroll
        for (int mi = 0; mi < 4; mi++) {
            bf16x8 raw = *(const bf16x8*)(Ss + (w * 4 + mi) * 512 + quad * 128 + cn * 8);
            bf16x8 pf;
            float s = 0.f;
#pragma unroll
            for (int j = 0; j < 8; j++) {
                float e = __expf(b2f((u16)raw[j]) - mrow[mi]);
                s += e;
                pf[j] = (short)f2b(e);
            }
            ladd[mi] += s;
#pragma unroll
            for (int ni = 0; ni < 4; ni++)
                acc[mi][ni] = __builtin_amdgcn_mfma_f32_16x16x32_bf16(
                    pf, bfv[ni], acc[mi][ni], 0, 0, 0);
        }
        __syncthreads();
    }
#pragma unroll
    for (int mi = 0; mi < 4; mi++) {
        float l = ladd[mi];
        l += __shfl_xor(l, 16);
        l += __shfl_xor(l, 32);
        if (quad == 0) atomicAdd(&Lsum[head * 256 + w * 64 + mi * 16 + cn], l);
#pragma unroll
        for (int ni = 0; ni < 4; ni++)
#pragma unroll
            for (int r = 0; r < 4; r++) {
                int row = w * 64 + mi * 16 + quad * 4 + r;
                atomicAdd(&O[((long)head * 256 + row) * 64 + ni * 16 + cn],
                          acc[mi][ni][r]);
            }
    }
}

__global__ void divide_ol(float* __restrict__ O, const float* __restrict__ L) {
    int idx = blockIdx.x * 256 + threadIdx.x;  // 8*256*64
    O[idx] = O[idx] / L[idx >> 6];
}

// ================= fused sim1 -> softmax -> @W2 -> +conv -> bf16 ==============
__global__ __launch_bounds__(256) void attn1_fused(
    const u16* __restrict__ Qb, const u16* __restrict__ KLb,
    const u16* __restrict__ W2T, const float* __restrict__ CONV,
    u16* __restrict__ OUTb) {
    __shared__ u16 lds[32768] __attribute__((aligned(16)));
    u16* Qs = lds;             // [2 c][4 w][512]
    u16* KLs = lds + 4096;     // [2 c][16 chunks][512]
    u16* Ps = lds;             // [8 c][4 seg][64 rows][8]
    u16* W2s = lds + 16384;    // [8 c][4 chunks][512]
    int tid = threadIdx.x, lane = tid & 63, w = tid >> 6;
    int head = blockIdx.y, n0 = blockIdx.x * 64;
    int quad = lane >> 4, cn = lane & 15;
    int lr = lane & 15, lc = (lane >> 4) << 3;
    const u16* Qh = Qb + (long)head * 16384 * 64;
    const u16* KLh = KLb + (long)head * 256 * 64;
    const u16* W2h = W2T + (long)head * 64 * 256;
#pragma unroll
    for (int c = 0; c < 2; c++)
        gl_lds16(Qh + (long)(n0 + w * 16 + lr) * 64 + c * 32 + lc,
                 Qs + c * 2048 + w * 512 + lane * 8);
#pragma unroll
    for (int c = 0; c < 2; c++)
#pragma unroll
        for (int rg = 0; rg < 4; rg++) {
            int chunk = rg * 4 + w;
            gl_lds16(KLh + (long)(chunk * 16 + lr) * 64 + c * 32 + lc,
                     KLs + c * 8192 + chunk * 512 + lane * 8);
        }
    __syncthreads();
    // S = Q @ KL^T : wave owns 16 rows, 256 cols
    f32x4 acc[16];
#pragma unroll
    for (int i = 0; i < 16; i++) acc[i] = (f32x4){0.f, 0.f, 0.f, 0.f};
#pragma unroll
    for (int c = 0; c < 2; c++) {
        bf16x8 af = *(const bf16x8*)(Qs + c * 2048 + w * 512 + quad * 128 + cn * 8);
#pragma unroll
        for (int ni = 0; ni < 16; ni++) {
            bf16x8 bfv = *(const bf16x8*)(KLs + c * 8192 + ni * 512 + quad * 128 + cn * 8);
            acc[ni] = __builtin_amdgcn_mfma_f32_16x16x32_bf16(af, bfv, acc[ni], 0, 0, 0);
        }
    }
    __syncthreads();  // all reads of Qs/KLs done before Ps overwrite
    // softmax rows (quad owns rows quad*4+r), write P bf16 to [c][seg][64r][8]
#pragma unroll
    for (int r = 0; r < 4; r++) {
        float mx = -1e30f;
#pragma unroll
        for (int ni = 0; ni < 16; ni++) mx = fmaxf(mx, acc[ni][r]);
        mx = fmaxf(mx, __shfl_xor(mx, 1));
        mx = fmaxf(mx, __shfl_xor(mx, 2));
        mx = fmaxf(mx, __shfl_xor(mx, 4));
        mx = fmaxf(mx, __shfl_xor(mx, 8));
        float e[16];
        float s = 0.f;
#pragma unroll
        for (int ni = 0; ni < 16; ni++) {
            e[ni] = __expf(acc[ni][r] - mx);
            s += e[ni];
        }
        s += __shfl_xor(s, 1);
        s += __shfl_xor(s, 2);
        s += __shfl_xor(s, 4);
        s += __shfl_xor(s, 8);
        float inv = 1.f / s;
        int prow = w * 16 + quad * 4 + r;
#pragma unroll
        for (int ni = 0; ni < 16; ni++) {
            int k = ni * 16 + cn;
            Ps[(k >> 5) * 2048 + ((k >> 3) & 3) * 512 + prow * 8 + (k & 7)] =
                f2b(e[ni] * inv);
        }
    }
#pragma unroll
    for (int c = 0; c < 8; c++)
        gl_lds16(W2h + (long)(w * 16 + lr) * 256 + c * 32 + lc,
                 W2s + c * 2048 + w * 512 + lane * 8);
    __syncthreads();
    // O = P @ W2 (64 cols)
    f32x4 acc2[4];
#pragma unroll
    for (int i = 0; i < 4; i++) acc2[i] = (f32x4){0.f, 0.f, 0.f, 0.f};
#pragma unroll
    for (int c = 0; c < 8; c++) {
        bf16x8 af = *(const bf16x8*)(Ps + c * 2048 + quad * 512 + (w * 16 + cn) * 8);
#pragma unroll
        for (int ni = 0; ni < 4; ni++) {
            bf16x8 bfv = *(const bf16x8*)(W2s + c * 2048 + ni * 512 + quad * 128 + cn * 8);
            acc2[ni] = __builtin_amdgcn_mfma_f32_16x16x32_bf16(af, bfv, acc2[ni], 0, 0, 0);
        }
    }
#pragma unroll
    for (int ni = 0; ni < 4; ni++)
#pragma unroll
        for (int r = 0; r < 4; r++) {
            int row = n0 + w * 16 + quad * 4 + r;
            long idx = (long)row * 512 + head * 64 + ni * 16 + cn;
            OUTb[idx] = f2b(CONV[idx] + acc2[ni][r]);
        }
}

// ================= fp32 tile GEMM (pinv xz / W2) ===============================
#define TILE 64
#define KT 16
#define LDP (TILE + 4)
__global__ __launch_bounds__(256) void gemm_kernel(
    const float* __restrict__ A, const float* __restrict__ B, float* __restrict__ C,
    int M, int N, int K, int lda, int ldb, int ldc,
    long sA, long sB, long sC, int tilesN) {
    int tm = blockIdx.x / tilesN, tn = blockIdx.x % tilesN;
    int batch = blockIdx.y;
    A += (long)batch * sA; B += (long)batch * sB; C += (long)batch * sC;
    int row0 = tm * TILE, col0 = tn * TILE;
    __shared__ float As[KT][LDP];
    __shared__ float Bs[KT][LDP];
    int t = threadIdx.x;
    int tx = t & 15, ty = t >> 4;
    float acc[4][4] = {{0.f}};
    int aRow = t >> 2, aK = (t & 3) << 2;
    int bN = t & 63, bK = (t >> 6) << 2;
    for (int k0 = 0; k0 < K; k0 += KT) {
        {
            int r = row0 + aRow;
            float4 av = make_float4(0.f, 0.f, 0.f, 0.f);
            if (r < M) av = *(const float4*)(A + (long)r * lda + k0 + aK);
            As[aK][aRow] = av.x; As[aK + 1][aRow] = av.y;
            As[aK + 2][aRow] = av.z; As[aK + 3][aRow] = av.w;
        }
        {
            const float* bp = B + (long)(k0 + bK) * ldb + col0 + bN;
            bool ok = col0 + bN < N;
#pragma unroll
            for (int j = 0; j < 4; j++) Bs[bK + j][bN] = ok ? bp[(long)j * ldb] : 0.f;
        }
        __syncthreads();
#pragma unroll
        for (int kk = 0; kk < KT; kk++) {
            float4 a = *(const float4*)&As[kk][ty << 2];
            float4 b = *(const float4*)&Bs[kk][tx << 2];
            acc[0][0] += a.x * b.x; acc[0][1] += a.x * b.y; acc[0][2] += a.x * b.z; acc[0][3] += a.x * b.w;
            acc[1][0] += a.y * b.x; acc[1][1] += a.y * b.y; acc[1][2] += a.y * b.z; acc[1][3] += a.y * b.w;
            acc[2][0] += a.z * b.x; acc[2][1] += a.z * b.y; acc[2][2] += a.z * b.z; acc[2][3] += a.z * b.w;
            acc[3][0] += a.w * b.x; acc[3][1] += a.w * b.y; acc[3][2] += a.w * b.z; acc[3][3] += a.w * b.w;
        }
        __syncthreads();
    }
#pragma unroll
    for (int i = 0; i < 4; i++) {
        int row = row0 + (ty << 2) + i;
        if (row >= M) continue;
        float* cp = C + (long)row * ldc + col0 + (tx << 2);
#pragma unroll
        for (int j = 0; j < 4; j++) {
            int col = col0 + (tx << 2) + j;
            if (col >= N) continue;
            cp[j] = acc[i][j];
        }
    }
}
static void gemm32(hipStream_t st, int M, int N, int K,
                   const float* A, int lda, long sA,
                   const float* B, int ldb, long sB,
                   float* C, int ldc, long sC, int batch) {
    int tilesM = (M + TILE - 1) / TILE, tilesN = (N + TILE - 1) / TILE;
    dim3 grid(tilesM * tilesN, batch);
    gemm_kernel<<<grid, 256, 0, st>>>(A, B, C, M, N, K, lda, ldb, ldc, sA, sB, sC, tilesN);
}

// ================= pinv fused chain ============================================
__global__ __launch_bounds__(256) void pinv_chain(const float* __restrict__ xz,
                                                  const float* __restrict__ z,
                                                  float* __restrict__ zn) {
    int h = blockIdx.y, c0 = blockIdx.x * 8;
    const float* X = xz + (long)h * 65536;
    const float* Z = z + (long)h * 65536;
    __shared__ float ta[256][8];
    __shared__ float tb[256][8];
    int t = threadIdx.x;
    const float4* X4 = (const float4*)(X + t * 256);
    const float4* Z4 = (const float4*)(Z + t * 256);
    float acc[8];
#pragma unroll
    for (int j = 0; j < 8; j++)
        ta[t][j] = ((t == c0 + j) ? 7.f : 0.f) - X[t * 256 + c0 + j];
    __syncthreads();
#pragma unroll
    for (int j = 0; j < 8; j++) acc[j] = 0.f;
    for (int k4 = 0; k4 < 64; k4++) {
        float4 xv = X4[k4];
#pragma unroll
        for (int j = 0; j < 8; j++)
            acc[j] += xv.x * ta[k4 * 4][j] + xv.y * ta[k4 * 4 + 1][j] +
                      xv.z * ta[k4 * 4 + 2][j] + xv.w * ta[k4 * 4 + 3][j];
    }
#pragma unroll
    for (int j = 0; j < 8; j++)
        tb[t][j] = ((t == c0 + j) ? 15.f : 0.f) - acc[j];
    __syncthreads();
#pragma unroll
    for (int j = 0; j < 8; j++) acc[j] = 0.f;
    for (int k4 = 0; k4 < 64; k4++) {
        float4 xv = X4[k4];
#pragma unroll
        for (int j = 0; j < 8; j++)
            acc[j] += xv.x * tb[k4 * 4][j] + xv.y * tb[k4 * 4 + 1][j] +
                      xv.z * tb[k4 * 4 + 2][j] + xv.w * tb[k4 * 4 + 3][j];
    }
    __syncthreads();
#pragma unroll
    for (int j = 0; j < 8; j++)
        ta[t][j] = ((t == c0 + j) ? 13.f : 0.f) - acc[j];
    __syncthreads();
#pragma unroll
    for (int j = 0; j < 8; j++) acc[j] = 0.f;
    for (int k4 = 0; k4 < 64; k4++) {
        float4 zv = Z4[k4];
#pragma unroll
        for (int j = 0; j < 8; j++)
            acc[j] += zv.x * ta[k4 * 4][j] + zv.y * ta[k4 * 4 + 1][j] +
                      zv.z * ta[k4 * 4 + 2][j] + zv.w * ta[k4 * 4 + 3][j];
    }
#pragma unroll
    for (int j = 0; j < 8; j++)
        zn[(long)h * 65536 + t * 256 + c0 + j] = 0.25f * acc[j];
}

// ================= layernorm / softmax / misc =================================
__global__ __launch_bounds__(256) void layernorm_bf16(
    const float* __restrict__ x, const float* __restrict__ g,
    const float* __restrict__ b, u16* __restrict__ y) {
    __shared__ float sm[4];
    long base = (long)blockIdx.x * 512;
    int t = threadIdx.x;
    float v0 = x[base + t], v1 = x[base + 256 + t];
    float s = wred_sum(v0 + v1);
    if ((t & 63) == 0) sm[t >> 6] = s;
    __syncthreads();
    float mu = (sm[0] + sm[1] + sm[2] + sm[3]) * (1.f / 512.f);
    __syncthreads();
    float d0 = v0 - mu, d1 = v1 - mu;
    float q = wred_sum(d0 * d0 + d1 * d1);
    if ((t & 63) == 0) sm[t >> 6] = q;
    __syncthreads();
    float var = (sm[0] + sm[1] + sm[2] + sm[3]) * (1.f / 512.f);
    float rstd = rsqrtf(var + 1e-5f);
    y[base + t] = f2b(d0 * rstd * g[t] + b[t]);
    y[base + 256 + t] = f2b(d1 * rstd * g[256 + t] + b[256 + t]);
}

__global__ __launch_bounds__(256) void softmax_rows(float* __restrict__ data, int ncols) {
    __shared__ float sm[4];
    float* row = data + (long)blockIdx.x * ncols;
    int t = threadIdx.x;
    float m = -1e30f;
    for (int c = t; c < ncols; c += 256) m = fmaxf(m, row[c]);
    m = wred_max(m);
    if ((t & 63) == 0) sm[t >> 6] = m;
    __syncthreads();
    m = fmaxf(fmaxf(sm[0], sm[1]), fmaxf(sm[2], sm[3]));
    __syncthreads();
    float s = 0.f;
    for (int c = t; c < ncols; c += 256) {
        float e = __expf(row[c] - m);
        row[c] = e;
        s += e;
    }
    s = wred_sum(s);
    if ((t & 63) == 0) sm[t >> 6] = s;
    __syncthreads();
    s = sm[0] + sm[1] + sm[2] + sm[3];
    float inv = 1.f / s;
    for (int c = t; c < ncols; c += 256) row[c] *= inv;
}

__global__ void cls_copy(const float* __restrict__ cls, float* __restrict__ X) {
    X[threadIdx.x] = cls[threadIdx.x];
}
__global__ void build_hb(const float* __restrict__ h, u16* __restrict__ dst) {
    long idx = (long)blockIdx.x * 256 + threadIdx.x;
    long row = idx >> 10;
    int col = (int)(idx & 1023);
    float v = (row == 0) ? 0.f : h[((row - 1) << 10) + col];
    dst[idx] = f2b(v);
}
__global__ void transpose_to_bf16(const float* __restrict__ src, u16* __restrict__ dst,
                                  int R, int C) {
    long idx = (long)blockIdx.x * 256 + threadIdx.x;
    if (idx >= (long)R * C) return;
    int r = (int)(idx / C), c = (int)(idx % C);
    dst[(long)c * R + r] = f2b(src[idx]);
}
__global__ __launch_bounds__(256) void transpose_v(const u16* __restrict__ Vb,
                                                   u16* __restrict__ VT) {
    __shared__ u16 tile[64][68];
    int h = blockIdx.y, n0 = blockIdx.x * 64;
    int t = threadIdx.x;
    int i = t >> 2, seg = t & 3;
    const u16* src = Vb + ((long)h * 16384 + n0 + i) * 64 + seg * 16;
#pragma unroll
    for (int j = 0; j < 16; j++) tile[seg * 16 + j][i] = src[j];
    __syncthreads();
    u16* dst = VT + ((long)h * 64 + i) * 16384 + n0 + seg * 16;
#pragma unroll
    for (int j = 0; j < 16; j++) dst[j] = tile[i][seg * 16 + j];
}
__global__ void landmarks_b(const u16* __restrict__ Qb, const u16* __restrict__ Kb,
                            u16* __restrict__ QLb, u16* __restrict__ KLb) {
    int h = blockIdx.x >> 8, j = blockIdx.x & 255, d = threadIdx.x;
    const u16* qb = Qb + ((long)h * 16384 + j * 64) * 64 + d;
    const u16* kb = Kb + ((long)h * 16384 + j * 64) * 64 + d;
    float sq = 0.f, sk = 0.f;
    for (int tk = 0; tk < 64; ++tk) {
        sq += b2f(qb[tk * 64]);
        sk += b2f(kb[tk * 64]);
    }
    QLb[((h << 8) + j) * 64 + d] = f2b(sq * (1.f / 64.f));
    KLb[((h << 8) + j) * 64 + d] = f2b(sk * (1.f / 64.f));
}
__global__ __launch_bounds__(256) void pinv_absmax(const float* __restrict__ a2,
                                                   float* __restrict__ maxes) {
    __shared__ float sm[4];
    const float* Xh = a2 + (long)blockIdx.x * 65536;
    int t = threadIdx.x;
    float cs = 0.f, rs = 0.f;
    for (int j = 0; j < 256; j++) {
        cs += fabsf(Xh[t * 256 + j]);
        rs += fabsf(Xh[j * 256 + t]);
    }
    float cm = wred_max(cs);
    if ((t & 63) == 0) sm[t >> 6] = cm;
    __syncthreads();
    cm = fmaxf(fmaxf(sm[0], sm[1]), fmaxf(sm[2], sm[3]));
    if (t == 0) atomicMax((int*)&maxes[0], __float_as_int(cm));
    __syncthreads();
    float rm = wred_max(rs);
    if ((t & 63) == 0) sm[t >> 6] = rm;
    __syncthreads();
    rm = fmaxf(fmaxf(sm[0], sm[1]), fmaxf(sm[2], sm[3]));
    if (t == 0) atomicMax((int*)&maxes[1], __float_as_int(rm));
}
__global__ void pinv_init(const float* __restrict__ a2, const float* __restrict__ maxes,
                          float* __restrict__ z) {
    long idx = (long)blockIdx.x * 256 + threadIdx.x;
    int h = (int)(idx >> 16);
    int rem = (int)(idx & 65535);
    int i = rem >> 8, j = rem & 255;
    float inv = 1.f / (maxes[0] * maxes[1]);
    z[idx] = a2[((long)h << 16) + (j << 8) + i] * inv;
}
__global__ __launch_bounds__(256) void conv_kernel(const u16* __restrict__ VT,
                                                   const float* __restrict__ cw,
                                                   float* __restrict__ out) {
    int h = blockIdx.y;
    int n0 = blockIdx.x * 64;
    __shared__ float vt[64][97];
    int t = threadIdx.x;
    for (int i = t; i < 64 * 96; i += 256) {
        int d = i / 96, j = i % 96;
        int n = n0 - 16 + j;
        float v = 0.f;
        if (n >= 0 && n < 16384) v = b2f(VT[((long)h * 64 + d) * 16384 + n]);
        vt[d][j] = v;
    }
    __syncthreads();
    float w[33];
#pragma unroll
    for (int k = 0; k < 33; k++) w[k] = cw[h * 33 + k];
    int d = t & 63, ty = t >> 6;
    for (int nn = 0; nn < 16; nn++) {
        int nl = ty * 16 + nn;
        float s = 0.f;
#pragma unroll
        for (int k = 0; k < 33; k++) s += w[k] * vt[d][nl + k];
        out[((long)(n0 + nl)) * 512 + h * 64 + d] = s;
    }
}
__global__ void w2t_kernel(const float* __restrict__ W2, u16* __restrict__ W2T) {
    int idx = blockIdx.x * 256 + threadIdx.x;  // 8*256*64
    int h = idx >> 14, rem = idx & 16383, m = rem >> 6, d = rem & 63;
    W2T[(h << 14) + (d << 8) + m] = f2b(W2[idx]);
}
__global__ __launch_bounds__(256) void final_head(
    const float* __restrict__ X, const float* __restrict__ g, const float* __restrict__ b,
    const float* __restrict__ W, const float* __restrict__ bias, float* __restrict__ out) {
    __shared__ float sm[4];
    __shared__ float ln0[512];
    int t = threadIdx.x;
    float v0 = X[t], v1 = X[256 + t];
    float s = wred_sum(v0 + v1);
    if ((t & 63) == 0) sm[t >> 6] = s;
    __syncthreads();
    float mu = (sm[0] + sm[1] + sm[2] + sm[3]) * (1.f / 512.f);
    __syncthreads();
    float d0 = v0 - mu, d1 = v1 - mu;
    float q = wred_sum(d0 * d0 + d1 * d1);
    if ((t & 63) == 0) sm[t >> 6] = q;
    __syncthreads();
    float rstd = rsqrtf((sm[0] + sm[1] + sm[2] + sm[3]) * (1.f / 512.f) + 1e-5f);
    ln0[t] = d0 * rstd * g[t] + b[t];
    ln0[256 + t] = d1 * rstd * g[256 + t] + b[256 + t];
    __syncthreads();
    int jj = blockIdx.x * 256 + t;
    if (jj < 1000) {
        float acc = bias[jj];
        for (int dd = 0; dd < 512; ++dd) acc += ln0[dd] * W[dd * 1000 + jj];
        out[jj] = acc;
    }
}

// ================= layer driver ================================================
struct Bufs {
    float *X, *LNA, *A2, *Z0, *Z1, *XZ, *O, *Lsum, *W2, *MAXES;
    u16 *LNb, *Qb, *Kb, *Vb, *VT, *QLb, *KLb, *W2T, *W1T, *QKVWT, *OUTWT, *Sb;
    unsigned* RMAX;
    int g;
};

static void run_layer(hipStream_t st, Bufs& B,
                      const float* ln_g, const float* ln_b, const float* qkv_W,
                      const float* conv_W, const float* out_W, const float* out_b) {
    const int N = 16384, D = 512, H = 8, DH = 64, M = 256;
    const long HS = (long)N * DH;
    GP p{};
    // 1. LN -> bf16
    layernorm_bf16<<<N, 256, 0, st>>>(B.X, ln_g, ln_b, B.LNb);
    // 2. qkv (row-major q/k/v epilogue), then VT transpose
    transpose_to_bf16<<<(512 * 1536 + 255) / 256, 256, 0, st>>>(qkv_W, B.QKVWT, 512, 1536);
    p = GP{}; p.A = B.LNb; p.B = B.QKVWT; p.Q = B.Qb; p.Kb = B.Kb; p.V = B.Vb; p.K = 512;
    launch_mgemm<128, 128, 4>(st, p, N, 1536, 1);
    transpose_v<<<dim3(256, 8), 256, 0, st>>>(B.Vb, B.VT);
    // 3. landmarks
    landmarks_b<<<H * M, 64, 0, st>>>(B.Qb, B.Kb, B.QLb, B.KLb);
    // 4. sim2 -> softmax -> pinv
    p = GP{}; p.A = B.QLb; p.B = B.KLb; p.C = B.A2; p.K = DH; p.ldc = M;
    p.sA = (long)M * DH; p.sB = (long)M * DH; p.sC = (long)M * M;
    launch_mgemm<128, 128, 0>(st, p, M, M, H);
    softmax_rows<<<H * M, 256, 0, st>>>(B.A2, M);
    hipMemsetAsync(B.MAXES, 0, 8, st);
    pinv_absmax<<<H, 256, 0, st>>>(B.A2, B.MAXES);
    pinv_init<<<(H * M * M) / 256, 256, 0, st>>>(B.A2, B.MAXES, B.Z0);
    float* z = B.Z0;
    float* zn = B.Z1;
    for (int it = 0; it < 6; ++it) {
        gemm32(st, M, M, M, B.A2, M, (long)M * M, z, M, (long)M * M,
               B.XZ, M, (long)M * M, H);
        pinv_chain<<<dim3(32, 8), 256, 0, st>>>(B.XZ, z, zn);
        float* tmp = z; z = zn; zn = tmp;
    }
    // 5. conv residual initializes ATTN (LNA)
    conv_kernel<<<dim3(N / 64, H), 256, 0, st>>>(B.VT, conv_W, B.LNA);
    // 6. sim3 pass A (bf16 S + rowmax) / pass B (flash consume) per head-group
    hipMemsetAsync(B.O, 0, (size_t)(8 * 256 * 64 + 8 * 256 + 8 * 256) * 4, st);
    int g = B.g;
    for (int hg = 0; hg < H; hg += g) {
        p = GP{}; p.A = B.QLb + (long)hg * M * DH; p.B = B.Kb + (long)hg * HS;
        p.Cb = B.Sb; p.rmax = B.RMAX + hg * 256; p.K = DH; p.ldc = N;
        p.sA = (long)M * DH; p.sB = HS; p.sC = (long)M * N;
        launch_mgemm<128, 128, 6>(st, p, M, N, g);
        a3v_flash<<<dim3(32, g), 256, 0, st>>>(B.Sb, B.VT, B.RMAX, B.O, B.Lsum, hg);
    }
    divide_ol<<<(H * M * DH) / 256, 256, 0, st>>>(B.O, B.Lsum);
    // 7. W2 = z @ a3v (fp32), transpose to bf16
    gemm32(st, M, DH, M, z, M, (long)M * M, B.O, DH, (long)M * DH,
           B.W2, DH, (long)M * DH, H);
    w2t_kernel<<<512, 256, 0, st>>>(B.W2, B.W2T);
    // 8. fused sim1 -> softmax -> @W2 -> +conv -> LNb (bf16)
    attn1_fused<<<dim3(N / 64, H), 256, 0, st>>>(B.Qb, B.KLb, B.W2T, B.LNA, B.LNb);
    // 9. out projection: X += ATTN @ out_W + out_b
    transpose_to_bf16<<<(512 * 512 + 255) / 256, 256, 0, st>>>(out_W, B.OUTWT, 512, 512);
    p = GP{}; p.A = B.LNb; p.B = B.OUTWT; p.C = B.X; p.bias = out_b; p.K = D; p.ldc = D;
    launch_mgemm<128, 128, 2>(st, p, N, D, 1);
}

extern "C" void kernel_launch(void* const* d_in, const int* in_sizes, int n_in,
                              void* d_out, int out_size, void* d_ws, size_t ws_size,
                              hipStream_t stream) {
    const float* h_in = (const float*)d_in[0];
    const float* W1 = (const float*)d_in[1];
    const float* b1 = (const float*)d_in[2];
    const float* cls = (const float*)d_in[3];
    const float* ln1_g = (const float*)d_in[4];
    const float* ln1_b = (const float*)d_in[5];
    const float* qkv1_W = (const float*)d_in[6];
    const float* conv1_W = (const float*)d_in[7];
    const float* out1_W = (const float*)d_in[8];
    const float* out1_b = (const float*)d_in[9];
    const float* ln2_g = (const float*)d_in[10];
    const float* ln2_b = (const float*)d_in[11];
    const float* qkv2_W = (const float*)d_in[12];
    const float* conv2_W = (const float*)d_in[13];
    const float* out2_W = (const float*)d_in[14];
    const float* out2_b = (const float*)d_in[15];
    const float* lnf_g = (const float*)d_in[16];
    const float* lnf_b = (const float*)d_in[17];
    const float* fc2_W = (const float*)d_in[18];
    const float* fc2_b = (const float*)d_in[19];
    float* out = (float*)d_out;

    char* wsb = (char*)d_ws;
    size_t off = 0;
    auto alloc = [&](size_t bytes) -> void* {
        void* p = (void*)(wsb + off);
        off += (bytes + 255) & ~(size_t)255;
        return p;
    };
    Bufs B;
    B.X    = (float*)alloc((size_t)16384 * 512 * 4);
    B.LNA  = (float*)alloc((size_t)16384 * 512 * 4);
    B.LNb  = (u16*)alloc((size_t)16384 * 512 * 2);
    B.Qb   = (u16*)alloc((size_t)8 * 16384 * 64 * 2);   // adjacent to Kb: HB alias
    B.Kb   = (u16*)alloc((size_t)8 * 16384 * 64 * 2);
    B.VT   = (u16*)alloc((size_t)8 * 64 * 16384 * 2);
    B.QLb  = (u16*)alloc((size_t)8 * 256 * 64 * 2);
    B.KLb  = (u16*)alloc((size_t)8 * 256 * 64 * 2);
    B.A2   = (float*)alloc((size_t)8 * 256 * 256 * 4);
    B.Z0   = (float*)alloc((size_t)8 * 256 * 256 * 4);
    B.Z1   = (float*)alloc((size_t)8 * 256 * 256 * 4);
    B.XZ   = (float*)alloc((size_t)8 * 256 * 256 * 4);
    B.O    = (float*)alloc((size_t)8 * 256 * 64 * 4);   // O, Lsum, RMAX contiguous
    B.Lsum = (float*)alloc((size_t)8 * 256 * 4);
    B.RMAX = (unsigned*)alloc((size_t)8 * 256 * 4);
    B.W2   = (float*)alloc((size_t)8 * 256 * 64 * 4);
    B.W2T  = (u16*)alloc((size_t)8 * 64 * 256 * 2);
    B.W1T  = (u16*)alloc((size_t)512 * 1024 * 2);
    B.QKVWT = (u16*)alloc((size_t)1536 * 512 * 2);
    B.OUTWT = (u16*)alloc((size_t)512 * 512 * 2);
    B.MAXES = (float*)alloc(256);
    size_t fixed = off;
    // union region: Vb (16 MB, dead after transpose_v) aliases Sb (g*8 MB)
    int g = 1;
    for (int cand = 8; cand >= 1; cand >>= 1) {
        size_t uni = (size_t)cand * 256 * 16384 * 2;
        if (uni < (size_t)16 * 1024 * 1024) uni = (size_t)16 * 1024 * 1024;
        if (ws_size >= fixed + uni + 4096) { g = cand; break; }
    }
    B.g = g;
    {
        size_t uni = (size_t)g * 256 * 16384 * 2;
        if (uni < (size_t)16 * 1024 * 1024) uni = (size_t)16 * 1024 * 1024;
        void* region = alloc(uni);
        B.Vb = (u16*)region;
        B.Sb = (u16*)region;
    }
    if (off > ws_size) return;  // fail loudly (output stays poisoned)

    // fc1: HB (aliases Qb..Kb, 32MB) = [0; h] bf16; X = relu(HB @ W1^T + b1); X[0]=cls
    u16* HB = B.Qb;
    build_hb<<<(16384 * 1024) / 256, 256, 0, stream>>>(h_in, HB);
    transpose_to_bf16<<<(1024 * 512 + 255) / 256, 256, 0, stream>>>(W1, B.W1T, 1024, 512);
    {
        GP p{}; p.A = HB; p.B = B.W1T; p.C = B.X; p.bias = b1; p.K = 1024; p.ldc = 512;
        launch_mgemm<128, 128, 1>(stream, p, 16384, 512, 1);
    }
    cls_copy<<<1, 512, 0, stream>>>(cls, B.X);

    run_layer(stream, B, ln1_g, ln1_b, qkv1_W, conv1_W, out1_W, out1_b);
    run_layer(stream, B, ln2_g, ln2_b, qkv2_W, conv2_W, out2_W, out2_b);

    final_head<<<4, 256, 0, stream>>>(B.X, lnf_g, lnf_b, fc2_W, fc2_b, out);
}

// Round 6
// 1633.393 us; speedup vs baseline: 3.2854x; 1.0115x over previous
//
#include <hip/hip_runtime.h>
#include <math.h>

typedef unsigned short u16;
typedef short bf16x8 __attribute__((ext_vector_type(8)));
typedef float f32x4 __attribute__((ext_vector_type(4)));

__device__ __forceinline__ u16 f2b(float x) {
    unsigned u = __builtin_bit_cast(unsigned, x);
    unsigned r = u + 0x7fffu + ((u >> 16) & 1u);
    return (u16)(r >> 16);
}
__device__ __forceinline__ float b2f(u16 v) {
    return __builtin_bit_cast(float, (unsigned)v << 16);
}
__device__ __forceinline__ void gl_lds16(const u16* g, u16* l) {
    __builtin_amdgcn_global_load_lds(
        (const __attribute__((address_space(1))) unsigned int*)g,
        (__attribute__((address_space(3))) unsigned int*)l, 16, 0, 0);
}
__device__ __forceinline__ float wred_sum(float v) {
#pragma unroll
    for (int o = 32; o > 0; o >>= 1) v += __shfl_down(v, o, 64);
    return v;
}
__device__ __forceinline__ float wred_max(float v) {
#pragma unroll
    for (int o = 32; o > 0; o >>= 1) v = fmaxf(v, __shfl_down(v, o, 64));
    return v;
}

// ================= bf16 MFMA GEMM (NT): C[M][N] = A[M][K] @ B[N][K]^T ==========
// LDS chunk layout [4 ksegs][16 rows][8]; conflict-free ds_read_b128.
// MODE: 0 plain fp32 C; 1 bias+relu; 2 C += acc + bias; 4 qkv-split bf16
struct GP {
    const u16* A; const u16* B; float* C;
    u16* Q; u16* Kb; u16* V;
    const float* bias;
    long sA, sB, sC;
    int K, ldc, tilesN;
};

template <int BM, int BN, int MODE>
__global__ __launch_bounds__(256) void mgemm(GP p) {
    constexpr int WN = BN / 64;
    constexpr int LA = BM / 64;
    constexpr int LB = BN / 64;
    __shared__ u16 As[BM * 32] __attribute__((aligned(16)));
    __shared__ u16 Bs[BN * 32] __attribute__((aligned(16)));

    int tid = threadIdx.x, lane = tid & 63, wave = tid >> 6;
    int wm = wave / WN, wn = wave % WN;
    int tm = blockIdx.x / p.tilesN, tn = blockIdx.x % p.tilesN;
    int batch = blockIdx.y;
    int m0 = tm * BM, n0 = tn * BN;
    const u16* A = p.A + (long)batch * p.sA;
    const u16* B = p.B + (long)batch * p.sB;

    f32x4 acc[4][4];
#pragma unroll
    for (int i = 0; i < 4; i++)
#pragma unroll
        for (int j = 0; j < 4; j++) acc[i][j] = (f32x4){0.f, 0.f, 0.f, 0.f};

    int lr = lane & 15;
    int lcb = (lane >> 4) << 3;
    int quad = lane >> 4, cn = lane & 15;
    for (int k0 = 0; k0 < p.K; k0 += 32) {
#pragma unroll
        for (int i = 0; i < LA; i++) {
            int chunk = wave * LA + i;
            gl_lds16(A + (long)(m0 + chunk * 16 + lr) * p.K + k0 + lcb,
                     As + chunk * 512 + lane * 8);
        }
#pragma unroll
        for (int i = 0; i < LB; i++) {
            int chunk = wave * LB + i;
            gl_lds16(B + (long)(n0 + chunk * 16 + lr) * p.K + k0 + lcb,
                     Bs + chunk * 512 + lane * 8);
        }
        __syncthreads();
        bf16x8 af[4], bfv[4];
#pragma unroll
        for (int mi = 0; mi < 4; mi++)
            af[mi] = *(const bf16x8*)(As + (wm * 4 + mi) * 512 + quad * 128 + cn * 8);
#pragma unroll
        for (int ni = 0; ni < 4; ni++)
            bfv[ni] = *(const bf16x8*)(Bs + (wn * 4 + ni) * 512 + quad * 128 + cn * 8);
#pragma unroll
        for (int mi = 0; mi < 4; mi++)
#pragma unroll
            for (int ni = 0; ni < 4; ni++)
                acc[mi][ni] = __builtin_amdgcn_mfma_f32_16x16x32_bf16(
                    af[mi], bfv[ni], acc[mi][ni], 0, 0, 0);
        __syncthreads();
    }

    if constexpr (MODE == 4) {
#pragma unroll
        for (int mi = 0; mi < 4; mi++) {
#pragma unroll
            for (int ni = 0; ni < 4; ni++) {
#pragma unroll
                for (int r = 0; r < 4; r++) {
                    int row = m0 + wm * 64 + mi * 16 + quad * 4 + r;
                    int col = n0 + wn * 64 + ni * 16 + cn;
                    float v = acc[mi][ni][r];
                    int h = col >> 6, d = col & 63;
                    if (col < 512)
                        p.Q[((long)h * 16384 + row) * 64 + d] = f2b(v * 0.125f);
                    else if (col < 1024)
                        p.Kb[((long)(h - 8) * 16384 + row) * 64 + d] = f2b(v);
                    else
                        p.V[((long)(h - 16) * 16384 + row) * 64 + d] = f2b(v);
                }
            }
        }
    } else {
        float* C = p.C + (long)batch * p.sC;
#pragma unroll
        for (int mi = 0; mi < 4; mi++) {
#pragma unroll
            for (int ni = 0; ni < 4; ni++) {
#pragma unroll
                for (int r = 0; r < 4; r++) {
                    int row = m0 + wm * 64 + mi * 16 + quad * 4 + r;
                    int col = n0 + wn * 64 + ni * 16 + cn;
                    float v = acc[mi][ni][r];
                    if (MODE == 0) {
                        C[(long)row * p.ldc + col] = v;
                    } else if (MODE == 1) {
                        C[(long)row * p.ldc + col] = fmaxf(v + p.bias[col], 0.f);
                    } else if (MODE == 2) {
                        C[(long)row * p.ldc + col] += v + p.bias[col];
                    }
                }
            }
        }
    }
}

template <int BM, int BN, int MODE>
static void launch_mgemm(hipStream_t st, GP p, int M, int N, int batch) {
    p.tilesN = N / BN;
    dim3 grid((M / BM) * (N / BN), batch);
    mgemm<BM, BN, MODE><<<grid, 256, 0, st>>>(p);
}

// ================= fused sim3 flash: O_partial = softmax-split(QL K^T) V ======
// grid (32 splits, 8 heads); block 256 thr. Per (head,split): 512 keys in
// 8 chunks of 64. Partials per split: m[256], l[256], O[256][64] fp32.
__global__ __launch_bounds__(256) void flash_a3v(
    const u16* __restrict__ QLb, const u16* __restrict__ Kb,
    const u16* __restrict__ VT, float* __restrict__ PART) {
    __shared__ u16 QLs[16384] __attribute__((aligned(16)));  // 16rc x 2kc chunks
    __shared__ u16 Ks[4096] __attribute__((aligned(16)));    // 4rc x 2kc
    __shared__ u16 Vs[4096] __attribute__((aligned(16)));    // 4dc x 2kc
    __shared__ u16 Ps[16384] __attribute__((aligned(16)));   // per-wave 4mi x 2kc
    int tid = threadIdx.x, lane = tid & 63, w = tid >> 6;
    int head = blockIdx.y, split = blockIdx.x;
    const u16* QLh = QLb + (long)head * 256 * 64;
    const u16* Kh = Kb + ((long)head * 16384 + split * 512) * 64;
    const u16* Vh = VT + (long)head * 64 * 16384 + split * 512;
    int quad = lane >> 4, cn = lane & 15;
    int lr = lane & 15, lc = (lane >> 4) << 3;

    for (int c = w; c < 32; c += 4) {
        int rc = c >> 1, kc = c & 1;
        gl_lds16(QLh + (long)(rc * 16 + lr) * 64 + kc * 32 + lc, QLs + c * 512 + lane * 8);
    }
    __syncthreads();
    bf16x8 qf[4][2];
#pragma unroll
    for (int mi = 0; mi < 4; mi++)
#pragma unroll
        for (int kc = 0; kc < 2; kc++)
            qf[mi][kc] = *(const bf16x8*)(QLs + ((w * 4 + mi) * 2 + kc) * 512 +
                                          quad * 128 + cn * 8);

    f32x4 Oacc[4][4];
    float m_i[4][4], l_i[4][4];
#pragma unroll
    for (int i = 0; i < 4; i++)
#pragma unroll
        for (int j = 0; j < 4; j++) {
            Oacc[i][j] = (f32x4){0.f, 0.f, 0.f, 0.f};
            m_i[i][j] = -1e30f;
            l_i[i][j] = 0.f;
        }

    for (int t = 0; t < 8; t++) {
        for (int i = w; i < 8; i += 4) {
            int rc = i >> 1, kc = i & 1;
            gl_lds16(Kh + (long)(t * 64 + rc * 16 + lr) * 64 + kc * 32 + lc,
                     Ks + i * 512 + lane * 8);
        }
        for (int i = w; i < 8; i += 4) {
            int dc = i >> 1, kc = i & 1;
            gl_lds16(Vh + (long)(dc * 16 + lr) * 16384 + t * 64 + kc * 32 + lc,
                     Vs + i * 512 + lane * 8);
        }
        __syncthreads();
        f32x4 s[4][4];
#pragma unroll
        for (int i = 0; i < 4; i++)
#pragma unroll
            for (int j = 0; j < 4; j++) s[i][j] = (f32x4){0.f, 0.f, 0.f, 0.f};
#pragma unroll
        for (int kc = 0; kc < 2; kc++) {
            bf16x8 kf[4];
#pragma unroll
            for (int ni = 0; ni < 4; ni++)
                kf[ni] = *(const bf16x8*)(Ks + (ni * 2 + kc) * 512 + quad * 128 + cn * 8);
#pragma unroll
            for (int mi = 0; mi < 4; mi++)
#pragma unroll
                for (int ni = 0; ni < 4; ni++)
                    s[mi][ni] = __builtin_amdgcn_mfma_f32_16x16x32_bf16(
                        qf[mi][kc], kf[ni], s[mi][ni], 0, 0, 0);
        }
        // online softmax per row (mi, r); write P bf16 to this wave's Ps region
#pragma unroll
        for (int mi = 0; mi < 4; mi++) {
#pragma unroll
            for (int r = 0; r < 4; r++) {
                float mx = fmaxf(fmaxf(s[mi][0][r], s[mi][1][r]),
                                 fmaxf(s[mi][2][r], s[mi][3][r]));
                mx = fmaxf(mx, __shfl_xor(mx, 1));
                mx = fmaxf(mx, __shfl_xor(mx, 2));
                mx = fmaxf(mx, __shfl_xor(mx, 4));
                mx = fmaxf(mx, __shfl_xor(mx, 8));
                float mold = m_i[mi][r];
                float mnew = fmaxf(mold, mx);
                float alpha = __expf(mold - mnew);
                m_i[mi][r] = mnew;
                float sum = 0.f;
#pragma unroll
                for (int ni = 0; ni < 4; ni++) {
                    float e = __expf(s[mi][ni][r] - mnew);
                    sum += e;
                    int col = ni * 16 + cn;
                    Ps[w * 4096 + (mi * 2 + (col >> 5)) * 512 + ((col >> 3) & 3) * 128 +
                       (quad * 4 + r) * 8 + (col & 7)] = f2b(e);
                    Oacc[mi][ni][r] *= alpha;
                }
                sum += __shfl_xor(sum, 1);
                sum += __shfl_xor(sum, 2);
                sum += __shfl_xor(sum, 4);
                sum += __shfl_xor(sum, 8);
                l_i[mi][r] = l_i[mi][r] * alpha + sum;
            }
        }
        __syncthreads();
        // PV: O += P @ V
#pragma unroll
        for (int kc = 0; kc < 2; kc++) {
            bf16x8 vf[4], pf[4];
#pragma unroll
            for (int nd = 0; nd < 4; nd++)
                vf[nd] = *(const bf16x8*)(Vs + (nd * 2 + kc) * 512 + quad * 128 + cn * 8);
#pragma unroll
            for (int mi = 0; mi < 4; mi++)
                pf[mi] = *(const bf16x8*)(Ps + w * 4096 + (mi * 2 + kc) * 512 +
                                          quad * 128 + cn * 8);
#pragma unroll
            for (int mi = 0; mi < 4; mi++)
#pragma unroll
                for (int nd = 0; nd < 4; nd++)
                    Oacc[mi][nd] = __builtin_amdgcn_mfma_f32_16x16x32_bf16(
                        pf[mi], vf[nd], Oacc[mi][nd], 0, 0, 0);
        }
        __syncthreads();
    }
    float* base = PART + ((long)head * 32 + split) * 16896;
#pragma unroll
    for (int mi = 0; mi < 4; mi++) {
#pragma unroll
        for (int r = 0; r < 4; r++) {
            int row = w * 64 + mi * 16 + quad * 4 + r;
            if (cn == 0) {
                base[row] = m_i[mi][r];
                base[256 + row] = l_i[mi][r];
            }
#pragma unroll
            for (int ni = 0; ni < 4; ni++)
                base[512 + row * 64 + ni * 16 + cn] = Oacc[mi][ni][r];
        }
    }
}

// combine partials: O[h][row][d] = sum_b exp(m_b-m) O_b / sum_b exp(m_b-m) l_b
__global__ __launch_bounds__(256) void a3v_combine(const float* __restrict__ PART,
                                                   float* __restrict__ O) {
    int head = blockIdx.x, rg = blockIdx.y;
    int t = threadIdx.x;
    int rl = t >> 6, d = t & 63;
    const float* ph = PART + (long)head * 32 * 16896;
    for (int rr = 0; rr < 16; rr++) {
        int row = rg * 64 + rr * 4 + rl;
        float m = -1e30f;
#pragma unroll 8
        for (int b = 0; b < 32; b++) m = fmaxf(m, ph[b * 16896 + row]);
        float l = 0.f, o = 0.f;
#pragma unroll 8
        for (int b = 0; b < 32; b++) {
            float a = __expf(ph[b * 16896 + row] - m);
            l += a * ph[b * 16896 + 256 + row];
            o += a * ph[b * 16896 + 512 + row * 64 + d];
        }
        O[((long)head * 256 + row) * 64 + d] = o / l;
    }
}

// ================= fused sim1 -> softmax -> @W2 -> +conv -> bf16 ==============
__global__ __launch_bounds__(256) void attn1_fused(
    const u16* __restrict__ Qb, const u16* __restrict__ KLb,
    const u16* __restrict__ W2T, const float* __restrict__ CONV,
    u16* __restrict__ OUTb) {
    __shared__ u16 lds[32768] __attribute__((aligned(16)));
    u16* Qs = lds;
    u16* KLs = lds + 4096;
    u16* Ps = lds;
    u16* W2s = lds + 16384;
    int tid = threadIdx.x, lane = tid & 63, w = tid >> 6;
    int head = blockIdx.y, n0 = blockIdx.x * 64;
    int quad = lane >> 4, cn = lane & 15;
    int lr = lane & 15, lc = (lane >> 4) << 3;
    const u16* Qh = Qb + (long)head * 16384 * 64;
    const u16* KLh = KLb + (long)head * 256 * 64;
    const u16* W2h = W2T + (long)head * 64 * 256;
#pragma unroll
    for (int c = 0; c < 2; c++)
        gl_lds16(Qh + (long)(n0 + w * 16 + lr) * 64 + c * 32 + lc,
                 Qs + c * 2048 + w * 512 + lane * 8);
#pragma unroll
    for (int c = 0; c < 2; c++)
#pragma unroll
        for (int rg = 0; rg < 4; rg++) {
            int chunk = rg * 4 + w;
            gl_lds16(KLh + (long)(chunk * 16 + lr) * 64 + c * 32 + lc,
                     KLs + c * 8192 + chunk * 512 + lane * 8);
        }
    __syncthreads();
    f32x4 acc[16];
#pragma unroll
    for (int i = 0; i < 16; i++) acc[i] = (f32x4){0.f, 0.f, 0.f, 0.f};
#pragma unroll
    for (int c = 0; c < 2; c++) {
        bf16x8 af = *(const bf16x8*)(Qs + c * 2048 + w * 512 + quad * 128 + cn * 8);
#pragma unroll
        for (int ni = 0; ni < 16; ni++) {
            bf16x8 bfv = *(const bf16x8*)(KLs + c * 8192 + ni * 512 + quad * 128 + cn * 8);
            acc[ni] = __builtin_amdgcn_mfma_f32_16x16x32_bf16(af, bfv, acc[ni], 0, 0, 0);
        }
    }
    __syncthreads();
#pragma unroll
    for (int r = 0; r < 4; r++) {
        float mx = -1e30f;
#pragma unroll
        for (int ni = 0; ni < 16; ni++) mx = fmaxf(mx, acc[ni][r]);
        mx = fmaxf(mx, __shfl_xor(mx, 1));
        mx = fmaxf(mx, __shfl_xor(mx, 2));
        mx = fmaxf(mx, __shfl_xor(mx, 4));
        mx = fmaxf(mx, __shfl_xor(mx, 8));
        float e[16];
        float s = 0.f;
#pragma unroll
        for (int ni = 0; ni < 16; ni++) {
            e[ni] = __expf(acc[ni][r] - mx);
            s += e[ni];
        }
        s += __shfl_xor(s, 1);
        s += __shfl_xor(s, 2);
        s += __shfl_xor(s, 4);
        s += __shfl_xor(s, 8);
        float inv = 1.f / s;
        int prow = w * 16 + quad * 4 + r;
#pragma unroll
        for (int ni = 0; ni < 16; ni++) {
            int k = ni * 16 + cn;
            Ps[(k >> 5) * 2048 + ((k >> 3) & 3) * 512 + prow * 8 + (k & 7)] =
                f2b(e[ni] * inv);
        }
    }
#pragma unroll
    for (int c = 0; c < 8; c++)
        gl_lds16(W2h + (long)(w * 16 + lr) * 256 + c * 32 + lc,
                 W2s + c * 2048 + w * 512 + lane * 8);
    __syncthreads();
    f32x4 acc2[4];
#pragma unroll
    for (int i = 0; i < 4; i++) acc2[i] = (f32x4){0.f, 0.f, 0.f, 0.f};
#pragma unroll
    for (int c = 0; c < 8; c++) {
        bf16x8 af = *(const bf16x8*)(Ps + c * 2048 + quad * 512 + (w * 16 + cn) * 8);
#pragma unroll
        for (int ni = 0; ni < 4; ni++) {
            bf16x8 bfv = *(const bf16x8*)(W2s + c * 2048 + ni * 512 + quad * 128 + cn * 8);
            acc2[ni] = __builtin_amdgcn_mfma_f32_16x16x32_bf16(af, bfv, acc2[ni], 0, 0, 0);
        }
    }
#pragma unroll
    for (int ni = 0; ni < 4; ni++)
#pragma unroll
        for (int r = 0; r < 4; r++) {
            int row = n0 + w * 16 + quad * 4 + r;
            long idx = (long)row * 512 + head * 64 + ni * 16 + cn;
            OUTb[idx] = f2b(CONV[idx] + acc2[ni][r]);
        }
}

// ================= fp32 tile GEMM (W2 = z @ a3v) ===============================
#define TILE 64
#define KT 16
#define LDP (TILE + 4)
__global__ __launch_bounds__(256) void gemm_kernel(
    const float* __restrict__ A, const float* __restrict__ B, float* __restrict__ C,
    int M, int N, int K, int lda, int ldb, int ldc,
    long sA, long sB, long sC, int tilesN) {
    int tm = blockIdx.x / tilesN, tn = blockIdx.x % tilesN;
    int batch = blockIdx.y;
    A += (long)batch * sA; B += (long)batch * sB; C += (long)batch * sC;
    int row0 = tm * TILE, col0 = tn * TILE;
    __shared__ float As[KT][LDP];
    __shared__ float Bs[KT][LDP];
    int t = threadIdx.x;
    int tx = t & 15, ty = t >> 4;
    float acc[4][4] = {{0.f}};
    int aRow = t >> 2, aK = (t & 3) << 2;
    int bN = t & 63, bK = (t >> 6) << 2;
    for (int k0 = 0; k0 < K; k0 += KT) {
        {
            int r = row0 + aRow;
            float4 av = make_float4(0.f, 0.f, 0.f, 0.f);
            if (r < M) av = *(const float4*)(A + (long)r * lda + k0 + aK);
            As[aK][aRow] = av.x; As[aK + 1][aRow] = av.y;
            As[aK + 2][aRow] = av.z; As[aK + 3][aRow] = av.w;
        }
        {
            const float* bp = B + (long)(k0 + bK) * ldb + col0 + bN;
            bool ok = col0 + bN < N;
#pragma unroll
            for (int j = 0; j < 4; j++) Bs[bK + j][bN] = ok ? bp[(long)j * ldb] : 0.f;
        }
        __syncthreads();
#pragma unroll
        for (int kk = 0; kk < KT; kk++) {
            float4 a = *(const float4*)&As[kk][ty << 2];
            float4 b = *(const float4*)&Bs[kk][tx << 2];
            acc[0][0] += a.x * b.x; acc[0][1] += a.x * b.y; acc[0][2] += a.x * b.z; acc[0][3] += a.x * b.w;
            acc[1][0] += a.y * b.x; acc[1][1] += a.y * b.y; acc[1][2] += a.y * b.z; acc[1][3] += a.y * b.w;
            acc[2][0] += a.z * b.x; acc[2][1] += a.z * b.y; acc[2][2] += a.z * b.z; acc[2][3] += a.z * b.w;
            acc[3][0] += a.w * b.x; acc[3][1] += a.w * b.y; acc[3][2] += a.w * b.z; acc[3][3] += a.w * b.w;
        }
        __syncthreads();
    }
#pragma unroll
    for (int i = 0; i < 4; i++) {
        int row = row0 + (ty << 2) + i;
        if (row >= M) continue;
        float* cp = C + (long)row * ldc + col0 + (tx << 2);
#pragma unroll
        for (int j = 0; j < 4; j++) {
            int col = col0 + (tx << 2) + j;
            if (col >= N) continue;
            cp[j] = acc[i][j];
        }
    }
}
static void gemm32(hipStream_t st, int M, int N, int K,
                   const float* A, int lda, long sA,
                   const float* B, int ldb, long sB,
                   float* C, int ldc, long sC, int batch) {
    int tilesM = (M + TILE - 1) / TILE, tilesN = (N + TILE - 1) / TILE;
    dim3 grid(tilesM * tilesN, batch);
    gemm_kernel<<<grid, 256, 0, st>>>(A, B, C, M, N, K, lda, ldb, ldc, sA, sB, sC, tilesN);
}

// ================= pinv fused chain (fp32; also emits z^T bf16) ================
__global__ __launch_bounds__(256) void pinv_chain(const float* __restrict__ xz,
                                                  const float* __restrict__ z,
                                                  float* __restrict__ zn,
                                                  u16* __restrict__ znT) {
    int h = blockIdx.y, c0 = blockIdx.x * 8;
    const float* X = xz + (long)h * 65536;
    const float* Z = z + (long)h * 65536;
    __shared__ float ta[256][8];
    __shared__ float tb[256][8];
    int t = threadIdx.x;
    const float4* X4 = (const float4*)(X + t * 256);
    const float4* Z4 = (const float4*)(Z + t * 256);
    float acc[8];
#pragma unroll
    for (int j = 0; j < 8; j++)
        ta[t][j] = ((t == c0 + j) ? 7.f : 0.f) - X[t * 256 + c0 + j];
    __syncthreads();
#pragma unroll
    for (int j = 0; j < 8; j++) acc[j] = 0.f;
    for (int k4 = 0; k4 < 64; k4++) {
        float4 xv = X4[k4];
#pragma unroll
        for (int j = 0; j < 8; j++)
            acc[j] += xv.x * ta[k4 * 4][j] + xv.y * ta[k4 * 4 + 1][j] +
                      xv.z * ta[k4 * 4 + 2][j] + xv.w * ta[k4 * 4 + 3][j];
    }
#pragma unroll
    for (int j = 0; j < 8; j++)
        tb[t][j] = ((t == c0 + j) ? 15.f : 0.f) - acc[j];
    __syncthreads();
#pragma unroll
    for (int j = 0; j < 8; j++) acc[j] = 0.f;
    for (int k4 = 0; k4 < 64; k4++) {
        float4 xv = X4[k4];
#pragma unroll
        for (int j = 0; j < 8; j++)
            acc[j] += xv.x * tb[k4 * 4][j] + xv.y * tb[k4 * 4 + 1][j] +
                      xv.z * tb[k4 * 4 + 2][j] + xv.w * tb[k4 * 4 + 3][j];
    }
    __syncthreads();
#pragma unroll
    for (int j = 0; j < 8; j++)
        ta[t][j] = ((t == c0 + j) ? 13.f : 0.f) - acc[j];
    __syncthreads();
#pragma unroll
    for (int j = 0; j < 8; j++) acc[j] = 0.f;
    for (int k4 = 0; k4 < 64; k4++) {
        float4 zv = Z4[k4];
#pragma unroll
        for (int j = 0; j < 8; j++)
            acc[j] += zv.x * ta[k4 * 4][j] + zv.y * ta[k4 * 4 + 1][j] +
                      zv.z * ta[k4 * 4 + 2][j] + zv.w * ta[k4 * 4 + 3][j];
    }
#pragma unroll
    for (int j = 0; j < 8; j++) {
        float v = 0.25f * acc[j];
        zn[(long)h * 65536 + t * 256 + c0 + j] = v;
        znT[(long)h * 65536 + (c0 + j) * 256 + t] = f2b(v);
    }
}

// ================= layernorm / softmax / misc =================================
__global__ __launch_bounds__(256) void layernorm_bf16(
    const float* __restrict__ x, const float* __restrict__ g,
    const float* __restrict__ b, u16* __restrict__ y) {
    __shared__ float sm[4];
    long base = (long)blockIdx.x * 512;
    int t = threadIdx.x;
    float v0 = x[base + t], v1 = x[base + 256 + t];
    float s = wred_sum(v0 + v1);
    if ((t & 63) == 0) sm[t >> 6] = s;
    __syncthreads();
    float mu = (sm[0] + sm[1] + sm[2] + sm[3]) * (1.f / 512.f);
    __syncthreads();
    float d0 = v0 - mu, d1 = v1 - mu;
    float q = wred_sum(d0 * d0 + d1 * d1);
    if ((t & 63) == 0) sm[t >> 6] = q;
    __syncthreads();
    float var = (sm[0] + sm[1] + sm[2] + sm[3]) * (1.f / 512.f);
    float rstd = rsqrtf(var + 1e-5f);
    y[base + t] = f2b(d0 * rstd * g[t] + b[t]);
    y[base + 256 + t] = f2b(d1 * rstd * g[256 + t] + b[256 + t]);
}

// softmax fp32 in place; also writes bf16 copy
__global__ __launch_bounds__(256) void softmax_rows(float* __restrict__ data,
                                                    u16* __restrict__ outb, int ncols) {
    __shared__ float sm[4];
    float* row = data + (long)blockIdx.x * ncols;
    u16* rowb = outb + (long)blockIdx.x * ncols;
    int t = threadIdx.x;
    float m = -1e30f;
    for (int c = t; c < ncols; c += 256) m = fmaxf(m, row[c]);
    m = wred_max(m);
    if ((t & 63) == 0) sm[t >> 6] = m;
    __syncthreads();
    m = fmaxf(fmaxf(sm[0], sm[1]), fmaxf(sm[2], sm[3]));
    __syncthreads();
    float s = 0.f;
    for (int c = t; c < ncols; c += 256) {
        float e = __expf(row[c] - m);
        row[c] = e;
        s += e;
    }
    s = wred_sum(s);
    if ((t & 63) == 0) sm[t >> 6] = s;
    __syncthreads();
    s = sm[0] + sm[1] + sm[2] + sm[3];
    float inv = 1.f / s;
    for (int c = t; c < ncols; c += 256) {
        float v = row[c] * inv;
        row[c] = v;
        rowb[c] = f2b(v);
    }
}

__global__ void cls_copy(const float* __restrict__ cls, float* __restrict__ X) {
    X[threadIdx.x] = cls[threadIdx.x];
}
__global__ void build_hb(const float* __restrict__ h, u16* __restrict__ dst) {
    long idx = (long)blockIdx.x * 256 + threadIdx.x;
    long row = idx >> 10;
    int col = (int)(idx & 1023);
    float v = (row == 0) ? 0.f : h[((row - 1) << 10) + col];
    dst[idx] = f2b(v);
}
__global__ void transpose_to_bf16(const float* __restrict__ src, u16* __restrict__ dst,
                                  int R, int C) {
    long idx = (long)blockIdx.x * 256 + threadIdx.x;
    if (idx >= (long)R * C) return;
    int r = (int)(idx / C), c = (int)(idx % C);
    dst[(long)c * R + r] = f2b(src[idx]);
}
__global__ __launch_bounds__(256) void transpose_v(const u16* __restrict__ Vb,
                                                   u16* __restrict__ VT) {
    __shared__ u16 tile[64][68];
    int h = blockIdx.y, n0 = blockIdx.x * 64;
    int t = threadIdx.x;
    int i = t >> 2, seg = t & 3;
    const u16* src = Vb + ((long)h * 16384 + n0 + i) * 64 + seg * 16;
#pragma unroll
    for (int j = 0; j < 16; j++) tile[seg * 16 + j][i] = src[j];
    __syncthreads();
    u16* dst = VT + ((long)h * 64 + i) * 16384 + n0 + seg * 16;
#pragma unroll
    for (int j = 0; j < 16; j++) dst[j] = tile[i][seg * 16 + j];
}
__global__ void landmarks_b(const u16* __restrict__ Qb, const u16* __restrict__ Kb,
                            u16* __restrict__ QLb, u16* __restrict__ KLb) {
    int h = blockIdx.x >> 8, j = blockIdx.x & 255, d = threadIdx.x;
    const u16* qb = Qb + ((long)h * 16384 + j * 64) * 64 + d;
    const u16* kb = Kb + ((long)h * 16384 + j * 64) * 64 + d;
    float sq = 0.f, sk = 0.f;
    for (int tk = 0; tk < 64; ++tk) {
        sq += b2f(qb[tk * 64]);
        sk += b2f(kb[tk * 64]);
    }
    QLb[((h << 8) + j) * 64 + d] = f2b(sq * (1.f / 64.f));
    KLb[((h << 8) + j) * 64 + d] = f2b(sk * (1.f / 64.f));
}
__global__ __launch_bounds__(256) void pinv_absmax(const float* __restrict__ a2,
                                                   float* __restrict__ maxes) {
    __shared__ float sm[4];
    const float* Xh = a2 + (long)blockIdx.x * 65536;
    int t = threadIdx.x;
    float cs = 0.f, rs = 0.f;
    for (int j = 0; j < 256; j++) {
        cs += fabsf(Xh[t * 256 + j]);
        rs += fabsf(Xh[j * 256 + t]);
    }
    float cm = wred_max(cs);
    if ((t & 63) == 0) sm[t >> 6] = cm;
    __syncthreads();
    cm = fmaxf(fmaxf(sm[0], sm[1]), fmaxf(sm[2], sm[3]));
    if (t == 0) atomicMax((int*)&maxes[0], __float_as_int(cm));
    __syncthreads();
    float rm = wred_max(rs);
    if ((t & 63) == 0) sm[t >> 6] = rm;
    __syncthreads();
    rm = fmaxf(fmaxf(sm[0], sm[1]), fmaxf(sm[2], sm[3]));
    if (t == 0) atomicMax((int*)&maxes[1], __float_as_int(rm));
}
// z0 = a2^T * s (fp32) and z0^T bf16 (= a2 * s)
__global__ void pinv_init(const float* __restrict__ a2, const float* __restrict__ maxes,
                          float* __restrict__ z, u16* __restrict__ zT) {
    long idx = (long)blockIdx.x * 256 + threadIdx.x;
    int h = (int)(idx >> 16);
    int rem = (int)(idx & 65535);
    int i = rem >> 8, j = rem & 255;
    float inv = 1.f / (maxes[0] * maxes[1]);
    float v = a2[((long)h << 16) + (j << 8) + i] * inv;
    z[idx] = v;
    zT[((long)h << 16) + (j << 8) + i] = f2b(v);
}
__global__ __launch_bounds__(256) void conv_kernel(const u16* __restrict__ VT,
                                                   const float* __restrict__ cw,
                                                   float* __restrict__ out) {
    int h = blockIdx.y;
    int n0 = blockIdx.x * 64;
    __shared__ float vt[64][97];
    int t = threadIdx.x;
    for (int i = t; i < 64 * 96; i += 256) {
        int d = i / 96, j = i % 96;
        int n = n0 - 16 + j;
        float v = 0.f;
        if (n >= 0 && n < 16384) v = b2f(VT[((long)h * 64 + d) * 16384 + n]);
        vt[d][j] = v;
    }
    __syncthreads();
    float w[33];
#pragma unroll
    for (int k = 0; k < 33; k++) w[k] = cw[h * 33 + k];
    int d = t & 63, ty = t >> 6;
    for (int nn = 0; nn < 16; nn++) {
        int nl = ty * 16 + nn;
        float s = 0.f;
#pragma unroll
        for (int k = 0; k < 33; k++) s += w[k] * vt[d][nl + k];
        out[((long)(n0 + nl)) * 512 + h * 64 + d] = s;
    }
}
__global__ void w2t_kernel(const float* __restrict__ W2, u16* __restrict__ W2T) {
    int idx = blockIdx.x * 256 + threadIdx.x;  // 8*256*64
    int h = idx >> 14, rem = idx & 16383, m = rem >> 6, d = rem & 63;
    W2T[(h << 14) + (d << 8) + m] = f2b(W2[idx]);
}
__global__ __launch_bounds__(256) void final_head(
    const float* __restrict__ X, const float* __restrict__ g, const float* __restrict__ b,
    const float* __restrict__ W, const float* __restrict__ bias, float* __restrict__ out) {
    __shared__ float sm[4];
    __shared__ float ln0[512];
    int t = threadIdx.x;
    float v0 = X[t], v1 = X[256 + t];
    float s = wred_sum(v0 + v1);
    if ((t & 63) == 0) sm[t >> 6] = s;
    __syncthreads();
    float mu = (sm[0] + sm[1] + sm[2] + sm[3]) * (1.f / 512.f);
    __syncthreads();
    float d0 = v0 - mu, d1 = v1 - mu;
    float q = wred_sum(d0 * d0 + d1 * d1);
    if ((t & 63) == 0) sm[t >> 6] = q;
    __syncthreads();
    float rstd = rsqrtf((sm[0] + sm[1] + sm[2] + sm[3]) * (1.f / 512.f) + 1e-5f);
    ln0[t] = d0 * rstd * g[t] + b[t];
    ln0[256 + t] = d1 * rstd * g[256 + t] + b[256 + t];
    __syncthreads();
    int jj = blockIdx.x * 256 + t;
    if (jj < 1000) {
        float acc = bias[jj];
        for (int dd = 0; dd < 512; ++dd) acc += ln0[dd] * W[dd * 1000 + jj];
        out[jj] = acc;
    }
}

// ================= layer driver ================================================
struct Bufs {
    float *X, *LNA, *A2, *Z0, *Z1, *XZ, *O, *W2, *MAXES, *PART;
    u16 *LNb, *Qb, *Kb, *Vb, *VT, *QLb, *KLb, *W2T, *W1T, *QKVWT, *OUTWT;
    u16 *A2b, *ZT0, *ZT1;
};

static void run_layer(hipStream_t st, Bufs& B,
                      const float* ln_g, const float* ln_b, const float* qkv_W,
                      const float* conv_W, const float* out_W, const float* out_b) {
    const int N = 16384, D = 512, H = 8, DH = 64, M = 256;
    GP p{};
    // 1. LN -> bf16
    layernorm_bf16<<<N, 256, 0, st>>>(B.X, ln_g, ln_b, B.LNb);
    // 2. qkv (row-major q/k/v epilogue), then VT transpose
    transpose_to_bf16<<<(512 * 1536 + 255) / 256, 256, 0, st>>>(qkv_W, B.QKVWT, 512, 1536);
    p = GP{}; p.A = B.LNb; p.B = B.QKVWT; p.Q = B.Qb; p.Kb = B.Kb; p.V = B.Vb; p.K = 512;
    launch_mgemm<128, 128, 4>(st, p, N, 1536, 1);
    transpose_v<<<dim3(256, 8), 256, 0, st>>>(B.Vb, B.VT);
    // 3. landmarks
    landmarks_b<<<H * M, 64, 0, st>>>(B.Qb, B.Kb, B.QLb, B.KLb);
    // 4. sim2 -> softmax (fp32 + bf16 copy) -> pinv
    p = GP{}; p.A = B.QLb; p.B = B.KLb; p.C = B.A2; p.K = DH; p.ldc = M;
    p.sA = (long)M * DH; p.sB = (long)M * DH; p.sC = (long)M * M;
    launch_mgemm<128, 128, 0>(st, p, M, M, H);
    softmax_rows<<<H * M, 256, 0, st>>>(B.A2, B.A2b, M);
    hipMemsetAsync(B.MAXES, 0, 8, st);
    pinv_absmax<<<H, 256, 0, st>>>(B.A2, B.MAXES);
    pinv_init<<<(H * M * M) / 256, 256, 0, st>>>(B.A2, B.MAXES, B.Z0, B.ZT0);
    float* z = B.Z0; float* zn = B.Z1;
    u16* zt = B.ZT0; u16* ztn = B.ZT1;
    for (int it = 0; it < 6; ++it) {
        // XZ = a2 @ z via bf16 MFMA (NT with z^T)
        p = GP{}; p.A = B.A2b; p.B = zt; p.C = B.XZ; p.K = M; p.ldc = M;
        p.sA = (long)M * M; p.sB = (long)M * M; p.sC = (long)M * M;
        launch_mgemm<128, 128, 0>(st, p, M, M, H);
        pinv_chain<<<dim3(32, 8), 256, 0, st>>>(B.XZ, z, zn, ztn);
        float* t1 = z; z = zn; zn = t1;
        u16* t2 = zt; zt = ztn; ztn = t2;
    }
    // 5. conv residual initializes ATTN (LNA)
    conv_kernel<<<dim3(N / 64, H), 256, 0, st>>>(B.VT, conv_W, B.LNA);
    // 6. fused sim3 flash (split over 32 key-ranges) + combine
    flash_a3v<<<dim3(32, 8), 256, 0, st>>>(B.QLb, B.Kb, B.VT, B.PART);
    a3v_combine<<<dim3(8, 4), 256, 0, st>>>(B.PART, B.O);
    // 7. W2 = z @ a3v (fp32), transpose to bf16
    gemm32(st, M, DH, M, z, M, (long)M * M, B.O, DH, (long)M * DH,
           B.W2, DH, (long)M * DH, H);
    w2t_kernel<<<512, 256, 0, st>>>(B.W2, B.W2T);
    // 8. fused sim1 -> softmax -> @W2 -> +conv -> LNb (bf16)
    attn1_fused<<<dim3(N / 64, H), 256, 0, st>>>(B.Qb, B.KLb, B.W2T, B.LNA, B.LNb);
    // 9. out projection: X += ATTN @ out_W + out_b
    transpose_to_bf16<<<(512 * 512 + 255) / 256, 256, 0, st>>>(out_W, B.OUTWT, 512, 512);
    p = GP{}; p.A = B.LNb; p.B = B.OUTWT; p.C = B.X; p.bias = out_b; p.K = D; p.ldc = D;
    launch_mgemm<128, 128, 2>(st, p, N, D, 1);
}

extern "C" void kernel_launch(void* const* d_in, const int* in_sizes, int n_in,
                              void* d_out, int out_size, void* d_ws, size_t ws_size,
                              hipStream_t stream) {
    const float* h_in = (const float*)d_in[0];
    const float* W1 = (const float*)d_in[1];
    const float* b1 = (const float*)d_in[2];
    const float* cls = (const float*)d_in[3];
    const float* ln1_g = (const float*)d_in[4];
    const float* ln1_b = (const float*)d_in[5];
    const float* qkv1_W = (const float*)d_in[6];
    const float* conv1_W = (const float*)d_in[7];
    const float* out1_W = (const float*)d_in[8];
    const float* out1_b = (const float*)d_in[9];
    const float* ln2_g = (const float*)d_in[10];
    const float* ln2_b = (const float*)d_in[11];
    const float* qkv2_W = (const float*)d_in[12];
    const float* conv2_W = (const float*)d_in[13];
    const float* out2_W = (const float*)d_in[14];
    const float* out2_b = (const float*)d_in[15];
    const float* lnf_g = (const float*)d_in[16];
    const float* lnf_b = (const float*)d_in[17];
    const float* fc2_W = (const float*)d_in[18];
    const float* fc2_b = (const float*)d_in[19];
    float* out = (float*)d_out;

    char* wsb = (char*)d_ws;
    size_t off = 0;
    auto alloc = [&](size_t bytes) -> void* {
        void* p = (void*)(wsb + off);
        off += (bytes + 255) & ~(size_t)255;
        return p;
    };
    Bufs B;
    B.X    = (float*)alloc((size_t)16384 * 512 * 4);
    B.LNA  = (float*)alloc((size_t)16384 * 512 * 4);
    B.LNb  = (u16*)alloc((size_t)16384 * 512 * 2);
    B.Qb   = (u16*)alloc((size_t)8 * 16384 * 64 * 2);   // adjacent to Kb: HB alias
    B.Kb   = (u16*)alloc((size_t)8 * 16384 * 64 * 2);
    B.VT   = (u16*)alloc((size_t)8 * 64 * 16384 * 2);
    B.QLb  = (u16*)alloc((size_t)8 * 256 * 64 * 2);
    B.KLb  = (u16*)alloc((size_t)8 * 256 * 64 * 2);
    B.A2   = (float*)alloc((size_t)8 * 256 * 256 * 4);
    B.A2b  = (u16*)alloc((size_t)8 * 256 * 256 * 2);
    B.Z0   = (float*)alloc((size_t)8 * 256 * 256 * 4);
    B.Z1   = (float*)alloc((size_t)8 * 256 * 256 * 4);
    B.ZT0  = (u16*)alloc((size_t)8 * 256 * 256 * 2);
    B.ZT1  = (u16*)alloc((size_t)8 * 256 * 256 * 2);
    B.XZ   = (float*)alloc((size_t)8 * 256 * 256 * 4);
    B.O    = (float*)alloc((size_t)8 * 256 * 64 * 4);
    B.W2   = (float*)alloc((size_t)8 * 256 * 64 * 4);
    B.W2T  = (u16*)alloc((size_t)8 * 64 * 256 * 2);
    B.W1T  = (u16*)alloc((size_t)512 * 1024 * 2);
    B.QKVWT = (u16*)alloc((size_t)1536 * 512 * 2);
    B.OUTWT = (u16*)alloc((size_t)512 * 512 * 2);
    B.MAXES = (float*)alloc(256);
    // union region: Vb (16 MB, dead after transpose_v) aliases PART (17.3 MB)
    {
        size_t vb = (size_t)8 * 16384 * 64 * 2;
        size_t part = (size_t)8 * 32 * 16896 * 4;
        void* region = alloc(part > vb ? part : vb);
        B.Vb = (u16*)region;
        B.PART = (float*)region;
    }
    if (off > ws_size) return;  // fail loudly (output stays poisoned)

    // fc1: HB (aliases Qb..Kb, 32MB) = [0; h] bf16; X = relu(HB @ W1^T + b1); X[0]=cls
    u16* HB = B.Qb;
    build_hb<<<(16384 * 1024) / 256, 256, 0, stream>>>(h_in, HB);
    transpose_to_bf16<<<(1024 * 512 + 255) / 256, 256, 0, stream>>>(W1, B.W1T, 1024, 512);
    {
        GP p{}; p.A = HB; p.B = B.W1T; p.C = B.X; p.bias = b1; p.K = 1024; p.ldc = 512;
        launch_mgemm<128, 128, 1>(stream, p, 16384, 512, 1);
    }
    cls_copy<<<1, 512, 0, stream>>>(cls, B.X);

    run_layer(stream, B, ln1_g, ln1_b, qkv1_W, conv1_W, out1_W, out1_b);
    run_layer(stream, B, ln2_g, ln2_b, qkv2_W, conv2_W, out2_W, out2_b);

    final_head<<<4, 256, 0, stream>>>(B.X, lnf_g, lnf_b, fc2_W, fc2_b, out);
}